// Round 9
// baseline (2694.978 us; speedup 1.0000x reference)
//
#include <hip/hip_runtime.h>
#include <hip/hip_bf16.h>

#define N_NODES 262144
#define N_EDGES 1048576
#define NC      30
#define ED      13
#define H       256
#define GH      512
#define OUT_C   256
#define NLAYERS 4
#define NGRAPHS 8192

typedef __hip_bfloat16 bf16;
typedef __attribute__((ext_vector_type(8))) short short8;   // 8 bf16 = 4 VGPR
typedef __attribute__((ext_vector_type(4))) float f32x4;

// packed weights: bf16, N-major (Bt[n][k], k contiguous) + fp32 biases
__device__ unsigned short g_W1t[H * H];
__device__ unsigned short g_Wl1t[2][H * H];
__device__ unsigned short g_Wl2t[2][H * H];
__device__ float g_b1[H];
__device__ float g_bl1[GH];
__device__ float g_bl2[OUT_C];
// CSR (device-resident so d_ws only needs hid+hsum = 256 MiB)
__device__ unsigned int g_ssrc[N_EDGES];          // 4 MiB, src ids dst-sorted
__device__ float        g_seat[N_EDGES * 16];     // 64 MiB, eattr dst-sorted, padded
__device__ unsigned int g_rowptr[N_NODES + 1];    // 1 MiB
__device__ unsigned int g_cursor[N_NODES];        // 1 MiB (hist cnt, then cursor)
__device__ unsigned int g_bsum[1024];

__device__ __forceinline__ float hw2f(unsigned short h) {
    return __uint_as_float(((unsigned int)h) << 16);
}
__device__ __forceinline__ float ldf(const void* p, size_t i, bool isbf) {
    return isbf ? hw2f(((const unsigned short*)p)[i]) : ((const float*)p)[i];
}
__device__ __forceinline__ int ldi(const void* p, size_t j, bool is64) {
    return ((const int*)p)[is64 ? 2 * j : j];   // little-endian lo word
}
__device__ __forceinline__ unsigned short bfbits(float f) {
    bf16 b = __float2bfloat16(f);
    return *(unsigned short*)&b;
}
__device__ __forceinline__ float lo16(unsigned int u) { return __uint_as_float(u << 16); }
__device__ __forceinline__ float hi16(unsigned int u) { return __uint_as_float(u & 0xFFFF0000u); }
__device__ __forceinline__ unsigned int pk2(float a, float b) {
    return (unsigned int)bfbits(a) | ((unsigned int)bfbits(b) << 16);
}
// float width sniff: even halfwords. bf16 data -> plausible exponents.
__device__ __forceinline__ bool sniff_bf16(const void* xv) {
    const unsigned short* q = (const unsigned short*)xv;
    int c = 0;
    for (int i = 0; i < 32; ++i) {
        unsigned short h = q[2 * i];
        int e = (h >> 7) & 0xFF;
        c += (h == 0 || (e >= 97 && e <= 141)) ? 1 : 0;
    }
    return c >= 20;
}
// int width sniff: odd 32-bit words all zero <=> int64 (values < 2^31).
__device__ __forceinline__ bool sniff_i64(const void* pv, size_t baseWord) {
    const unsigned int* q = (const unsigned int*)pv;
    int z = 0;
    for (int i = 0; i < 32; ++i) z += (q[baseWord + 2 * i + 1] == 0) ? 1 : 0;
    return z >= 20;
}
// async global->LDS, 16B per lane; dst is wave-uniform base + lane*16
__device__ __forceinline__ void gload_lds16(const void* g, void* l) {
    __builtin_amdgcn_global_load_lds(
        (const __attribute__((address_space(1))) unsigned int*)g,
        (__attribute__((address_space(3))) unsigned int*)l, 16, 0, 0);
}

// ---------------------------------------------------------------- fills
__global__ __launch_bounds__(256) void fill_f4(float4* p, int n4, float val) {
    int i = blockIdx.x * 256 + threadIdx.x;
    int stride = gridDim.x * 256;
    float4 z = make_float4(val, val, val, val);
    for (; i < n4; i += stride) p[i] = z;
}

// ---------------------------------------------------- weight / bias packers
// out[n][k] = in[k0+k][n0+n]  (transpose + bf16-normalize), 256x256 chunk
__global__ __launch_bounds__(256) void pack_wt(const void* __restrict__ in,
        int ldin, int k0, int n0, int which) {
    const bool isbf = sniff_bf16(in);
    unsigned short* outp = which == 0 ? g_W1t
                         : which == 1 ? g_Wl1t[0]
                         : which == 2 ? g_Wl1t[1]
                         : which == 3 ? g_Wl2t[0] : g_Wl2t[1];
    const int n = blockIdx.x, k = threadIdx.x;
    outp[(n << 8) + k] = bfbits(ldf(in, (size_t)(k0 + k) * ldin + n0 + n, isbf));
}
__global__ __launch_bounds__(256) void pack_bias(const void* b1, const void* bl1,
                                                 const void* bl2) {
    const int t = threadIdx.x;
    const bool s1 = sniff_bf16(b1), s2 = sniff_bf16(bl1), s3 = sniff_bf16(bl2);
    g_b1[t]        = ldf(b1,  t,       s1);
    g_bl1[t]       = ldf(bl1, t,       s2);
    g_bl1[t + 256] = ldf(bl1, t + 256, s2);
    g_bl2[t]       = ldf(bl2, t,       s3);
}

// ------------------------------------------------------------- CSR build
__global__ __launch_bounds__(256) void csr_zero() {
    g_cursor[blockIdx.x * 256 + threadIdx.x] = 0u;
}
__global__ __launch_bounds__(256) void hist_dst(const void* __restrict__ eidx) {
    const bool is64 = sniff_i64(eidx, 0);
    const int e = blockIdx.x * 256 + threadIdx.x;
    int dst = ldi(eidx, (size_t)N_EDGES + e, is64);
    if ((unsigned)dst >= (unsigned)N_NODES) dst = 0;
    atomicAdd(&g_cursor[dst], 1u);
}
__global__ __launch_bounds__(256) void scan1() {
    __shared__ unsigned int sh[256];
    const int tid = threadIdx.x;
    sh[tid] = g_cursor[blockIdx.x * 256 + tid];
    __syncthreads();
    for (int s = 128; s > 0; s >>= 1) {
        if (tid < s) sh[tid] += sh[tid + s];
        __syncthreads();
    }
    if (tid == 0) g_bsum[blockIdx.x] = sh[0];
}
__global__ __launch_bounds__(256) void scan2() {
    __shared__ unsigned int sh[1024];
    const int tid = threadIdx.x;
    for (int j = tid; j < 1024; j += 256) sh[j] = g_bsum[j];
    __syncthreads();
    if (tid == 0) {
        unsigned int run = 0;
        for (int j = 0; j < 1024; ++j) { unsigned int t = sh[j]; sh[j] = run; run += t; }
    }
    __syncthreads();
    for (int j = tid; j < 1024; j += 256) g_bsum[j] = sh[j];
}
__global__ __launch_bounds__(256) void scan3() {
    __shared__ unsigned int sh[256];
    const int tid = threadIdx.x;
    const int i = blockIdx.x * 256 + tid;
    const unsigned int v = g_cursor[i];
    sh[tid] = v;
    __syncthreads();
    for (int ofs = 1; ofs < 256; ofs <<= 1) {
        unsigned int t = (tid >= ofs) ? sh[tid - ofs] : 0u;
        __syncthreads();
        sh[tid] += t;
        __syncthreads();
    }
    const unsigned int excl = sh[tid] - v + g_bsum[blockIdx.x];
    g_rowptr[i] = excl;
    g_cursor[i] = excl;
    if (i == N_NODES - 1) g_rowptr[N_NODES] = excl + v;
}
// scatter src ids and edge_attr rows (fp32, padded to 16) into dst order
__global__ __launch_bounds__(256) void scatter_e(
        const void* __restrict__ eidx, const void* __restrict__ eattr) {
    const bool is64 = sniff_i64(eidx, 0);
    const bool isbf = sniff_bf16(eattr);
    const int e = blockIdx.x * 256 + threadIdx.x;
    int src = ldi(eidx, e, is64);
    int dst = ldi(eidx, (size_t)N_EDGES + e, is64);
    if ((unsigned)src >= (unsigned)N_NODES) src = 0;
    if ((unsigned)dst >= (unsigned)N_NODES) dst = 0;
    unsigned int pos = atomicAdd(&g_cursor[dst], 1u);
    if (pos >= (unsigned)N_EDGES) return;   // safety
    g_ssrc[pos] = (unsigned int)src;
    float a[16];
#pragma unroll
    for (int k = 0; k < ED; ++k) a[k] = ldf(eattr, (size_t)e * ED + k, isbf);
    a[13] = 0.f; a[14] = 0.f; a[15] = 0.f;
    float* so = g_seat + (size_t)pos * 16;
#pragma unroll
    for (int k = 0; k < 4; ++k)
        *(float4*)(so + 4 * k) = *(float4*)(a + 4 * k);
}

// ------------------------------------------------- hid = x @ W_nh + b_nh
__global__ __launch_bounds__(256) void node_proj(
        const void* __restrict__ x, const void* __restrict__ W,
        const void* __restrict__ b, bf16* __restrict__ hid) {
    const bool isbf = sniff_bf16(x);
    __shared__ float xs[16 * NC];
    const int m0 = blockIdx.x * 16;
    for (int i = threadIdx.x; i < 16 * NC; i += 256)
        xs[i] = ldf(x, (size_t)m0 * NC + i, isbf);
    __syncthreads();
    const int col = threadIdx.x;
    float w[NC];
#pragma unroll
    for (int k = 0; k < NC; ++k) w[k] = ldf(W, (size_t)k * H + col, isbf);
    const float bias = ldf(b, col, isbf);
#pragma unroll 4
    for (int r = 0; r < 16; ++r) {
        float acc = bias;
#pragma unroll
        for (int k = 0; k < NC; ++k) acc += xs[r * NC + k] * w[k];
        hid[(size_t)(m0 + r) * H + col] = __float2bfloat16(acc);
    }
}

// --------------------------------------------- CSR aggregation (no atomics)
// hsum[n] = hid[n] + sum_{e in in(n)} relu(hid[src(e)] + seat[e]@We + be)
// Wave-pair per node; lane owns ADJACENT cols c0=128*wh+2*lane, c1=c0+1.
// waves_per_eu(4,4): __launch_bounds__ min-waves only CAPS registers; the
// allocator still AIMS for max occupancy and chose 32 VGPR (R5-R7), forcing
// per-edge weight reloads (VMEM + ~80 VALU addr insts/edge, the measured
// 120 vs 36 hand-count gap). Pinning max waves/EU = 4 removes the incentive:
// the 26 weight floats can stay register-resident.
__global__ __launch_bounds__(256)
__attribute__((amdgpu_waves_per_eu(4, 4)))
void gine_agg(
        const void* __restrict__ We, size_t weOff,
        const void* __restrict__ be, size_t beOff,
        const unsigned short* __restrict__ hid,
        unsigned short* __restrict__ hsum) {
    const bool isbf = sniff_bf16(We);
    const int lane = threadIdx.x & 63;
    const int wave = threadIdx.x >> 6;
    const int wh   = wave & 1;       // which 128-col half
    const int wp   = wave >> 1;      // wave-pair id within block
    const int c0 = 128 * wh + 2 * lane;
    float w0[ED], w1[ED];
#pragma unroll
    for (int k = 0; k < ED; ++k) {
        const size_t o = weOff + (size_t)k * H;
        w0[k] = ldf(We, o + c0,     isbf);
        w1[k] = ldf(We, o + c0 + 1, isbf);
    }
    const float bb0 = ldf(be, beOff + c0,     isbf);
    const float bb1 = ldf(be, beOff + c0 + 1, isbf);

    const int nbase = blockIdx.x * 16 + wp * 8;
    for (int j = 0; j < 8; ++j) {
        const int node = nbase + j;
        const unsigned int r0 = __builtin_amdgcn_readfirstlane(g_rowptr[node]);
        const unsigned int r1 = __builtin_amdgcn_readfirstlane(g_rowptr[node + 1]);
        const unsigned int hu = *(const unsigned int*)(hid + (size_t)node * H + c0);
        float a0 = lo16(hu);
        float a1 = hi16(hu);
        unsigned int e = r0;
        for (; e + 2 <= r1; e += 2) {
            const unsigned int sA = __builtin_amdgcn_readfirstlane(g_ssrc[e]);
            const unsigned int sB = __builtin_amdgcn_readfirstlane(g_ssrc[e + 1]);
            const float* pA = g_seat + (size_t)e * 16;
            const float* pB = pA + 16;
            const unsigned int hA = *(const unsigned int*)(hid + (size_t)sA * H + c0);
            const unsigned int hB = *(const unsigned int*)(hid + (size_t)sB * H + c0);
            const float4 fA0 = *(const float4*)(pA);
            const float4 fA1 = *(const float4*)(pA + 4);
            const float4 fA2 = *(const float4*)(pA + 8);
            const float  fAc = pA[12];
            const float4 fB0 = *(const float4*)(pB);
            const float4 fB1 = *(const float4*)(pB + 4);
            const float4 fB2 = *(const float4*)(pB + 8);
            const float  fBc = pB[12];
            const float afA[ED] = {fA0.x, fA0.y, fA0.z, fA0.w, fA1.x, fA1.y,
                                   fA1.z, fA1.w, fA2.x, fA2.y, fA2.z, fA2.w, fAc};
            const float afB[ED] = {fB0.x, fB0.y, fB0.z, fB0.w, fB1.x, fB1.y,
                                   fB1.z, fB1.w, fB2.x, fB2.y, fB2.z, fB2.w, fBc};
            float mA0 = bb0, mA1 = bb1, mB0 = bb0, mB1 = bb1;
#pragma unroll
            for (int k = 0; k < ED; ++k) {
                mA0 += afA[k] * w0[k];
                mA1 += afA[k] * w1[k];
                mB0 += afB[k] * w0[k];
                mB1 += afB[k] * w1[k];
            }
            a0 += fmaxf(mA0 + lo16(hA), 0.f) + fmaxf(mB0 + lo16(hB), 0.f);
            a1 += fmaxf(mA1 + hi16(hA), 0.f) + fmaxf(mB1 + hi16(hB), 0.f);
        }
        if (e < r1) {   // odd tail
            const unsigned int s = __builtin_amdgcn_readfirstlane(g_ssrc[e]);
            const float* sp = g_seat + (size_t)e * 16;
            const unsigned int hs = *(const unsigned int*)(hid + (size_t)s * H + c0);
            const float4 f0 = *(const float4*)(sp);
            const float4 f1 = *(const float4*)(sp + 4);
            const float4 f2 = *(const float4*)(sp + 8);
            const float  fc = sp[12];
            const float af[ED] = {f0.x, f0.y, f0.z, f0.w, f1.x, f1.y, f1.z,
                                  f1.w, f2.x, f2.y, f2.z, f2.w, fc};
            float m0 = bb0, m1 = bb1;
#pragma unroll
            for (int k = 0; k < ED; ++k) {
                m0 += af[k] * w0[k];
                m1 += af[k] * w1[k];
            }
            a0 += fmaxf(m0 + lo16(hs), 0.f);
            a1 += fmaxf(m1 + hi16(hs), 0.f);
        }
        *(unsigned int*)(hsum + (size_t)node * H + c0) = pk2(a0, a1);
    }
}

// ------------------------------------------------------------ MFMA GEMM
// (R7 kernel, unchanged)
template <int MODE>
__global__ __launch_bounds__(256, 4) void gemm_mfma(
        const unsigned short* __restrict__ A, int bsel,
        unsigned short* __restrict__ Cb, float* __restrict__ Cf,
        const void* __restrict__ batch, size_t batOff, int doRelu, int useBias) {
    __shared__ unsigned short As[64 * 64];    // 8 KB, swizzled
    __shared__ unsigned short Bs[256 * 64];   // 32 KB, n-major [n][k], swizzled
    const int tid  = threadIdx.x;
    const int lane = tid & 63;
    const int wave = tid >> 6;
    const int m0   = blockIdx.x * 64;

    const unsigned short* Bt = bsel == 0 ? g_W1t
                             : bsel == 1 ? g_Wl1t[0]
                             : bsel == 2 ? g_Wl1t[1]
                             : bsel == 3 ? g_Wl2t[0] : g_Wl2t[1];
    const float* bias = bsel == 0 ? g_b1
                      : bsel == 1 ? g_bl1
                      : bsel == 2 ? g_bl1 + 256 : g_bl2;

    const int ar   = tid >> 2;
    const int ac   = (tid & 3) << 4;
    const int awb  = (ar << 7) + (ac << 1);
    const int aswz = (ar & 7) << 4;
    const size_t arow = (size_t)(m0 + ar) * H + ac;
    const int nrow = lane >> 3;
    const int kbu  = ((lane & 7) ^ nrow) << 4;

    f32x4 acc0[8], acc1[8];
    const f32x4 zz = {0.f, 0.f, 0.f, 0.f};
#pragma unroll
    for (int i = 0; i < 8; ++i) { acc0[i] = zz; acc1[i] = zz; }

    const int fr   = lane & 15;
    const int fg   = lane >> 4;
    const int rowb = (wave >> 1) << 5;   // 0 / 32
    const int colb = (wave & 1) << 7;    // 0 / 128

    for (int kt = 0; kt < 4; ++kt) {
#pragma unroll
        for (int j = 0; j < 8; ++j) {
            const int q = (wave << 3) + j;
            gload_lds16((const char*)Bt + (((size_t)(q << 3) + nrow) << 9)
                            + (kt << 7) + kbu,
                        (char*)Bs + (q << 10));
        }
        {
            const size_t aoff = arow + (kt << 6);
            uint4 w0 = *(const uint4*)(A + aoff);
            uint4 w1 = *(const uint4*)(A + aoff + 8);
            *(uint4*)((char*)As + (awb ^ aswz)) = w0;
            *(uint4*)((char*)As + ((awb + 16) ^ aswz)) = w1;
        }
        __syncthreads();   // drains vmcnt (global_load_lds) + lgkmcnt
#pragma unroll
        for (int s = 0; s < 2; ++s) {
            const int kofs = (s << 6) + (fg << 4);
            const int r0 = rowb + fr;
            short8 aF0 = *(const short8*)((const char*)As +
                          ((r0 << 7) + (kofs ^ ((r0 & 7) << 4))));
            short8 aF1 = *(const short8*)((const char*)As +
                          (((r0 + 16) << 7) + (kofs ^ ((r0 & 7) << 4))));
#pragma unroll
            for (int ct = 0; ct < 8; ++ct) {
                const int cc = colb + (ct << 4) + fr;
                short8 bF = *(const short8*)((const char*)Bs +
                             ((cc << 7) + (kofs ^ ((cc & 7) << 4))));
                acc0[ct] = __builtin_amdgcn_mfma_f32_16x16x32_bf16(aF0, bF, acc0[ct], 0, 0, 0);
                acc1[ct] = __builtin_amdgcn_mfma_f32_16x16x32_bf16(aF1, bF, acc1[ct], 0, 0, 0);
            }
        }
        __syncthreads();
    }

    const int crow = m0 + rowb + (fg << 2);
    if (MODE == 0) {
#pragma unroll
        for (int ct = 0; ct < 8; ++ct) {
            const int cc = colb + (ct << 4) + fr;
            const float bc = bias[cc];
#pragma unroll
            for (int r = 0; r < 4; ++r) {
                float v0 = acc0[ct][r] + bc;
                float v1 = acc1[ct][r] + bc;
                if (doRelu) { v0 = fmaxf(v0, 0.f); v1 = fmaxf(v1, 0.f); }
                Cb[(size_t)(crow + r) * H + cc]      = bfbits(v0);
                Cb[(size_t)(crow + 16 + r) * H + cc] = bfbits(v1);
            }
        }
    } else {
        const bool is64 = sniff_i64(batch, N_NODES / 2);
        int ga[5], gb[5];
#pragma unroll
        for (int r = 0; r < 4; ++r) {
            int g0 = ldi(batch, batOff + crow + r, is64);
            int g1 = ldi(batch, batOff + crow + 16 + r, is64);
            ga[r] = ((unsigned)g0 < (unsigned)NGRAPHS) ? g0 : 0;
            gb[r] = ((unsigned)g1 < (unsigned)NGRAPHS) ? g1 : 0;
        }
#pragma unroll
        for (int ct = 0; ct < 8; ++ct) {
            const int cc = colb + (ct << 4) + fr;
            const float bc = useBias ? bias[cc] : 0.f;
            float run0 = 0.f, run1 = 0.f;
#pragma unroll
            for (int r = 0; r < 4; ++r) {
                run0 += acc0[ct][r] + bc;
                if (r == 3 || ga[r + 1] != ga[r]) {
                    atomicAdd(&Cf[(size_t)ga[r] * OUT_C + cc], run0); run0 = 0.f;
                }
                run1 += acc1[ct][r] + bc;
                if (r == 3 || gb[r + 1] != gb[r]) {
                    atomicAdd(&Cf[(size_t)gb[r] * OUT_C + cc], run1); run1 = 0.f;
                }
            }
        }
    }
}

// ---------------------------------------------------------------- launcher
extern "C" void kernel_launch(void* const* d_in, const int* in_sizes, int n_in,
                              void* d_out, int out_size, void* d_ws, size_t ws_size,
                              hipStream_t stream) {
    const void *x = nullptr, *eattr = nullptr, *eidx = nullptr, *batch = nullptr;
    const void *W_nh = nullptr, *W1 = nullptr, *We = nullptr, *be = nullptr;
    const void *Wl1 = nullptr, *Wl2 = nullptr, *bl1 = nullptr;
    const void *z256[3] = {nullptr, nullptr, nullptr};
    int nz = 0;
    for (int i = 0; i < n_in; ++i) {
        switch (in_sizes[i]) {
            case N_NODES * NC:     x     = d_in[i]; break;
            case N_EDGES * ED:     eattr = d_in[i]; break;
            case 2 * N_EDGES:      eidx  = d_in[i]; break;
            case N_NODES:          batch = d_in[i]; break;
            case NC * H:           W_nh  = d_in[i]; break;
            case H * H:            W1    = d_in[i]; break;
            case NLAYERS * ED * H: We    = d_in[i]; break;
            case NLAYERS * H:      be    = d_in[i]; break;
            case H * GH:           if (!Wl1) Wl1 = d_in[i]; else Wl2 = d_in[i]; break;
            case GH:               bl1   = d_in[i]; break;
            case H:                if (nz < 3) z256[nz++] = d_in[i]; break;
            default: break;
        }
    }
    const void* b_nh = z256[0];
    const void* b1   = (nz > 1) ? z256[1] : z256[0];
    const void* bl2  = (nz > 2) ? z256[2] : z256[0];
    float* out = (float*)d_out;   // reference output dtype is FLOAT32

    if (!x || !eattr || !eidx || !batch || !W_nh || !W1 || !We || !be ||
        !Wl1 || !Wl2 || !bl1 || !b_nh) {
        fill_f4<<<1024, 256, 0, stream>>>((float4*)out, NGRAPHS * OUT_C / 4, 2.0e6f);
        return;  // sentinel: size-mapping failed
    }

    const size_t NH = (size_t)N_NODES * H;
    const size_t need = NH * 2 + NH * 2;   // hid + hsum, bf16 = 256 MiB
    if (ws_size < need) {
        fill_f4<<<1024, 256, 0, stream>>>((float4*)out, NGRAPHS * OUT_C / 4, 1.0e6f);
        return;  // sentinel: ws too small
    }
    bf16* hid            = (bf16*)d_ws;
    unsigned short* hsum = (unsigned short*)((char*)d_ws + NH * 2);

    // pack weights (transposed, bf16) + biases (fp32) into device globals
    pack_wt<<<256, 256, 0, stream>>>(W1,  H,     0,   0, 0);
    pack_wt<<<256, 256, 0, stream>>>(Wl1, GH,    0,   0, 1);
    pack_wt<<<256, 256, 0, stream>>>(Wl1, GH,    0, 256, 2);
    pack_wt<<<256, 256, 0, stream>>>(Wl2, OUT_C, 0,   0, 3);
    pack_wt<<<256, 256, 0, stream>>>(Wl2, OUT_C, 256, 0, 4);
    pack_bias<<<1, 256, 0, stream>>>(b1, bl1, bl2);

    // ---- build dst-sorted CSR once per launch (device-global storage)
    csr_zero<<<N_NODES / 256, 256, 0, stream>>>();
    hist_dst<<<N_EDGES / 256, 256, 0, stream>>>(eidx);
    scan1<<<N_NODES / 256, 256, 0, stream>>>();
    scan2<<<1, 256, 0, stream>>>();
    scan3<<<N_NODES / 256, 256, 0, stream>>>();
    scatter_e<<<N_EDGES / 256, 256, 0, stream>>>(eidx, eattr);

    node_proj<<<N_NODES / 16, 256, 0, stream>>>(x, W_nh, b_nh, hid);

    for (int l = 0; l < NLAYERS; ++l) {
        // hsum = hid + agg  (wave-pair per node, 2-edge unroll)
        gine_agg<<<N_NODES / 16, 256, 0, stream>>>(
            We, (size_t)l * ED * H, be, (size_t)l * H,
            (const unsigned short*)hid, hsum);
        // hid = relu(hsum @ W1 + b1)
        gemm_mfma<0><<<N_NODES / 64, 256, 0, stream>>>(
            hsum, 0, (unsigned short*)hid, nullptr, nullptr, 0, 1, 1);
    }

    // readout; t0 aliases hsum (dead after last layer GEMM consumed it)
    unsigned short* t0 = hsum;
    fill_f4<<<2048, 256, 0, stream>>>((float4*)out, NGRAPHS * OUT_C / 4, 0.f);
    for (int c = 0; c < 2; ++c) {
        gemm_mfma<0><<<N_NODES / 64, 256, 0, stream>>>(
            (const unsigned short*)hid, 1 + c,
            t0, nullptr, nullptr, 0, 1, 1);
        gemm_mfma<1><<<N_NODES / 64, 256, 0, stream>>>(
            t0, 3 + c,
            nullptr, out, batch, 0, 0, c == 0);
    }
}

// Round 10
// 2474.903 us; speedup vs baseline: 1.0889x; 1.0889x over previous
//
#include <hip/hip_runtime.h>
#include <hip/hip_bf16.h>

#define N_NODES 262144
#define N_EDGES 1048576
#define NC      30
#define ED      13
#define H       256
#define GH      512
#define OUT_C   256
#define NLAYERS 4
#define NGRAPHS 8192

typedef __hip_bfloat16 bf16;
typedef __attribute__((ext_vector_type(8))) short short8;   // 8 bf16 = 4 VGPR
typedef __attribute__((ext_vector_type(4))) float f32x4;

// packed weights: bf16, N-major (Bt[n][k], k contiguous) + fp32 biases
__device__ unsigned short g_W1t[H * H];
__device__ unsigned short g_Wl1t[2][H * H];
__device__ unsigned short g_Wl2t[2][H * H];
__device__ float g_b1[H];
__device__ float g_bl1[GH];
__device__ float g_bl2[OUT_C];
// CSR (device-resident so d_ws only needs hid+hsum = 256 MiB)
__device__ unsigned int g_ssrc[N_EDGES];          // 4 MiB, src ids dst-sorted
__device__ float        g_seat[N_EDGES * 16];     // 64 MiB, eattr dst-sorted, padded
__device__ unsigned int g_rowptr[N_NODES + 1];    // 1 MiB
__device__ unsigned int g_cursor[N_NODES];        // 1 MiB (hist cnt, then cursor)
__device__ unsigned int g_bsum[1024];

__device__ __forceinline__ float hw2f(unsigned short h) {
    return __uint_as_float(((unsigned int)h) << 16);
}
__device__ __forceinline__ float ldf(const void* p, size_t i, bool isbf) {
    return isbf ? hw2f(((const unsigned short*)p)[i]) : ((const float*)p)[i];
}
__device__ __forceinline__ int ldi(const void* p, size_t j, bool is64) {
    return ((const int*)p)[is64 ? 2 * j : j];   // little-endian lo word
}
__device__ __forceinline__ unsigned short bfbits(float f) {
    bf16 b = __float2bfloat16(f);
    return *(unsigned short*)&b;
}
__device__ __forceinline__ float lo16(unsigned int u) { return __uint_as_float(u << 16); }
__device__ __forceinline__ float hi16(unsigned int u) { return __uint_as_float(u & 0xFFFF0000u); }
__device__ __forceinline__ unsigned int pk2(float a, float b) {
    return (unsigned int)bfbits(a) | ((unsigned int)bfbits(b) << 16);
}
// float width sniff: even halfwords. bf16 data -> plausible exponents.
__device__ __forceinline__ bool sniff_bf16(const void* xv) {
    const unsigned short* q = (const unsigned short*)xv;
    int c = 0;
    for (int i = 0; i < 32; ++i) {
        unsigned short h = q[2 * i];
        int e = (h >> 7) & 0xFF;
        c += (h == 0 || (e >= 97 && e <= 141)) ? 1 : 0;
    }
    return c >= 20;
}
// int width sniff: odd 32-bit words all zero <=> int64 (values < 2^31).
__device__ __forceinline__ bool sniff_i64(const void* pv, size_t baseWord) {
    const unsigned int* q = (const unsigned int*)pv;
    int z = 0;
    for (int i = 0; i < 32; ++i) z += (q[baseWord + 2 * i + 1] == 0) ? 1 : 0;
    return z >= 20;
}
// async global->LDS, 16B per lane; dst is wave-uniform base + lane*16
__device__ __forceinline__ void gload_lds16(const void* g, void* l) {
    __builtin_amdgcn_global_load_lds(
        (const __attribute__((address_space(1))) unsigned int*)g,
        (__attribute__((address_space(3))) unsigned int*)l, 16, 0, 0);
}

// ---------------------------------------------------------------- fills
__global__ __launch_bounds__(256) void fill_f4(float4* p, int n4, float val) {
    int i = blockIdx.x * 256 + threadIdx.x;
    int stride = gridDim.x * 256;
    float4 z = make_float4(val, val, val, val);
    for (; i < n4; i += stride) p[i] = z;
}

// ---------------------------------------------------- weight / bias packers
// out[n][k] = in[k0+k][n0+n]  (transpose + bf16-normalize), 256x256 chunk
__global__ __launch_bounds__(256) void pack_wt(const void* __restrict__ in,
        int ldin, int k0, int n0, int which) {
    const bool isbf = sniff_bf16(in);
    unsigned short* outp = which == 0 ? g_W1t
                         : which == 1 ? g_Wl1t[0]
                         : which == 2 ? g_Wl1t[1]
                         : which == 3 ? g_Wl2t[0] : g_Wl2t[1];
    const int n = blockIdx.x, k = threadIdx.x;
    outp[(n << 8) + k] = bfbits(ldf(in, (size_t)(k0 + k) * ldin + n0 + n, isbf));
}
__global__ __launch_bounds__(256) void pack_bias(const void* b1, const void* bl1,
                                                 const void* bl2) {
    const int t = threadIdx.x;
    const bool s1 = sniff_bf16(b1), s2 = sniff_bf16(bl1), s3 = sniff_bf16(bl2);
    g_b1[t]        = ldf(b1,  t,       s1);
    g_bl1[t]       = ldf(bl1, t,       s2);
    g_bl1[t + 256] = ldf(bl1, t + 256, s2);
    g_bl2[t]       = ldf(bl2, t,       s3);
}

// ------------------------------------------------------------- CSR build
__global__ __launch_bounds__(256) void csr_zero() {
    g_cursor[blockIdx.x * 256 + threadIdx.x] = 0u;
}
__global__ __launch_bounds__(256) void hist_dst(const void* __restrict__ eidx) {
    const bool is64 = sniff_i64(eidx, 0);
    const int e = blockIdx.x * 256 + threadIdx.x;
    int dst = ldi(eidx, (size_t)N_EDGES + e, is64);
    if ((unsigned)dst >= (unsigned)N_NODES) dst = 0;
    atomicAdd(&g_cursor[dst], 1u);
}
__global__ __launch_bounds__(256) void scan1() {
    __shared__ unsigned int sh[256];
    const int tid = threadIdx.x;
    sh[tid] = g_cursor[blockIdx.x * 256 + tid];
    __syncthreads();
    for (int s = 128; s > 0; s >>= 1) {
        if (tid < s) sh[tid] += sh[tid + s];
        __syncthreads();
    }
    if (tid == 0) g_bsum[blockIdx.x] = sh[0];
}
__global__ __launch_bounds__(256) void scan2() {
    __shared__ unsigned int sh[1024];
    const int tid = threadIdx.x;
    for (int j = tid; j < 1024; j += 256) sh[j] = g_bsum[j];
    __syncthreads();
    if (tid == 0) {
        unsigned int run = 0;
        for (int j = 0; j < 1024; ++j) { unsigned int t = sh[j]; sh[j] = run; run += t; }
    }
    __syncthreads();
    for (int j = tid; j < 1024; j += 256) g_bsum[j] = sh[j];
}
__global__ __launch_bounds__(256) void scan3() {
    __shared__ unsigned int sh[256];
    const int tid = threadIdx.x;
    const int i = blockIdx.x * 256 + tid;
    const unsigned int v = g_cursor[i];
    sh[tid] = v;
    __syncthreads();
    for (int ofs = 1; ofs < 256; ofs <<= 1) {
        unsigned int t = (tid >= ofs) ? sh[tid - ofs] : 0u;
        __syncthreads();
        sh[tid] += t;
        __syncthreads();
    }
    const unsigned int excl = sh[tid] - v + g_bsum[blockIdx.x];
    g_rowptr[i] = excl;
    g_cursor[i] = excl;
    if (i == N_NODES - 1) g_rowptr[N_NODES] = excl + v;
}
// scatter src ids and edge_attr rows (fp32, padded to 16) into dst order
__global__ __launch_bounds__(256) void scatter_e(
        const void* __restrict__ eidx, const void* __restrict__ eattr) {
    const bool is64 = sniff_i64(eidx, 0);
    const bool isbf = sniff_bf16(eattr);
    const int e = blockIdx.x * 256 + threadIdx.x;
    int src = ldi(eidx, e, is64);
    int dst = ldi(eidx, (size_t)N_EDGES + e, is64);
    if ((unsigned)src >= (unsigned)N_NODES) src = 0;
    if ((unsigned)dst >= (unsigned)N_NODES) dst = 0;
    unsigned int pos = atomicAdd(&g_cursor[dst], 1u);
    if (pos >= (unsigned)N_EDGES) return;   // safety
    g_ssrc[pos] = (unsigned int)src;
    float a[16];
#pragma unroll
    for (int k = 0; k < ED; ++k) a[k] = ldf(eattr, (size_t)e * ED + k, isbf);
    a[13] = 0.f; a[14] = 0.f; a[15] = 0.f;
    float* so = g_seat + (size_t)pos * 16;
#pragma unroll
    for (int k = 0; k < 4; ++k)
        *(float4*)(so + 4 * k) = *(float4*)(a + 4 * k);
}

// ------------------------------------------------- hid = x @ W_nh + b_nh
__global__ __launch_bounds__(256) void node_proj(
        const void* __restrict__ x, const void* __restrict__ W,
        const void* __restrict__ b, bf16* __restrict__ hid) {
    const bool isbf = sniff_bf16(x);
    __shared__ float xs[16 * NC];
    const int m0 = blockIdx.x * 16;
    for (int i = threadIdx.x; i < 16 * NC; i += 256)
        xs[i] = ldf(x, (size_t)m0 * NC + i, isbf);
    __syncthreads();
    const int col = threadIdx.x;
    float w[NC];
#pragma unroll
    for (int k = 0; k < NC; ++k) w[k] = ldf(W, (size_t)k * H + col, isbf);
    const float bias = ldf(b, col, isbf);
#pragma unroll 4
    for (int r = 0; r < 16; ++r) {
        float acc = bias;
#pragma unroll
        for (int k = 0; k < NC; ++k) acc += xs[r * NC + k] * w[k];
        hid[(size_t)(m0 + r) * H + col] = __float2bfloat16(acc);
    }
}

// --------------------------------------------- CSR aggregation (no atomics)
// (exact R7 kernel — 270 µs proven. R9's waves_per_eu(4,4) raised VGPR 32->52
// but halved occupancy -> gather latency exposed, 372 µs. This kernel wants
// ~8 waves/SIMD TLP more than resident weights; register experiments closed.)
__global__ __launch_bounds__(256, 4) void gine_agg(
        const void* __restrict__ We, size_t weOff,
        const void* __restrict__ be, size_t beOff,
        const unsigned short* __restrict__ hid,
        unsigned short* __restrict__ hsum) {
    const bool isbf = sniff_bf16(We);
    const int lane = threadIdx.x & 63;
    const int wave = threadIdx.x >> 6;
    const int wh   = wave & 1;       // which 128-col half
    const int wp   = wave >> 1;      // wave-pair id within block
    const int c0 = 128 * wh + 2 * lane;
    float w0[ED], w1[ED];
#pragma unroll
    for (int k = 0; k < ED; ++k) {
        const size_t o = weOff + (size_t)k * H;
        w0[k] = ldf(We, o + c0,     isbf);
        w1[k] = ldf(We, o + c0 + 1, isbf);
    }
    const float bb0 = ldf(be, beOff + c0,     isbf);
    const float bb1 = ldf(be, beOff + c0 + 1, isbf);

    const int nbase = blockIdx.x * 16 + wp * 8;
    for (int j = 0; j < 8; ++j) {
        const int node = nbase + j;
        const unsigned int r0 = __builtin_amdgcn_readfirstlane(g_rowptr[node]);
        const unsigned int r1 = __builtin_amdgcn_readfirstlane(g_rowptr[node + 1]);
        const unsigned int hu = *(const unsigned int*)(hid + (size_t)node * H + c0);
        float a0 = lo16(hu);
        float a1 = hi16(hu);
        unsigned int e = r0;
        for (; e + 2 <= r1; e += 2) {
            const unsigned int sA = __builtin_amdgcn_readfirstlane(g_ssrc[e]);
            const unsigned int sB = __builtin_amdgcn_readfirstlane(g_ssrc[e + 1]);
            const float* pA = g_seat + (size_t)e * 16;
            const float* pB = pA + 16;
            const unsigned int hA = *(const unsigned int*)(hid + (size_t)sA * H + c0);
            const unsigned int hB = *(const unsigned int*)(hid + (size_t)sB * H + c0);
            const float4 fA0 = *(const float4*)(pA);
            const float4 fA1 = *(const float4*)(pA + 4);
            const float4 fA2 = *(const float4*)(pA + 8);
            const float  fAc = pA[12];
            const float4 fB0 = *(const float4*)(pB);
            const float4 fB1 = *(const float4*)(pB + 4);
            const float4 fB2 = *(const float4*)(pB + 8);
            const float  fBc = pB[12];
            const float afA[ED] = {fA0.x, fA0.y, fA0.z, fA0.w, fA1.x, fA1.y,
                                   fA1.z, fA1.w, fA2.x, fA2.y, fA2.z, fA2.w, fAc};
            const float afB[ED] = {fB0.x, fB0.y, fB0.z, fB0.w, fB1.x, fB1.y,
                                   fB1.z, fB1.w, fB2.x, fB2.y, fB2.z, fB2.w, fBc};
            float mA0 = bb0, mA1 = bb1, mB0 = bb0, mB1 = bb1;
#pragma unroll
            for (int k = 0; k < ED; ++k) {
                mA0 += afA[k] * w0[k];
                mA1 += afA[k] * w1[k];
                mB0 += afB[k] * w0[k];
                mB1 += afB[k] * w1[k];
            }
            a0 += fmaxf(mA0 + lo16(hA), 0.f) + fmaxf(mB0 + lo16(hB), 0.f);
            a1 += fmaxf(mA1 + hi16(hA), 0.f) + fmaxf(mB1 + hi16(hB), 0.f);
        }
        if (e < r1) {   // odd tail
            const unsigned int s = __builtin_amdgcn_readfirstlane(g_ssrc[e]);
            const float* sp = g_seat + (size_t)e * 16;
            const unsigned int hs = *(const unsigned int*)(hid + (size_t)s * H + c0);
            const float4 f0 = *(const float4*)(sp);
            const float4 f1 = *(const float4*)(sp + 4);
            const float4 f2 = *(const float4*)(sp + 8);
            const float  fc = sp[12];
            const float af[ED] = {f0.x, f0.y, f0.z, f0.w, f1.x, f1.y, f1.z,
                                  f1.w, f2.x, f2.y, f2.z, f2.w, fc};
            float m0 = bb0, m1 = bb1;
#pragma unroll
            for (int k = 0; k < ED; ++k) {
                m0 += af[k] * w0[k];
                m1 += af[k] * w1[k];
            }
            a0 += fmaxf(m0 + lo16(hs), 0.f);
            a1 += fmaxf(m1 + hi16(hs), 0.f);
        }
        *(unsigned int*)(hsum + (size_t)node * H + c0) = pk2(a0, a1);
    }
}

// ------------------------------------------------------------ MFMA GEMM
// BM=128: per k-slice 12 ds_read_b128 (~144 cyc LDS pipe) vs 32 MFMA
// (~160 cyc matrix pipe) -> matrix-bound (BM=64 was 10 reads / 16 MFMA =
// LDS-read-bound at ~130 µs/dispatch, 2.6x the 41 µs traffic floor).
// __launch_bounds__(256, 1): THE fix for R6's regression — default bounds
// target 8 waves/SIMD => ~64 VGPR => the 128-float acc SPILLED. Min-1 lets
// the allocator hold acc[4][8]+frags (~200 VGPR) in registers; LDS 48 KB
// limits to 3 blocks/CU which is fine for an MFMA-bound loop.
// MODE 0: Cb = bf16(act(..)).  MODE 1: fp32 atomicAdd pooled by batch[].
template <int MODE>
__global__ __launch_bounds__(256, 1) void gemm_mfma(
        const unsigned short* __restrict__ A, int bsel,
        unsigned short* __restrict__ Cb, float* __restrict__ Cf,
        const void* __restrict__ batch, size_t batOff, int doRelu, int useBias) {
    __shared__ unsigned short As[128 * 64];   // 16 KB, swizzled
    __shared__ unsigned short Bs[256 * 64];   // 32 KB, n-major [n][k], swizzled
    const int tid  = threadIdx.x;
    const int lane = tid & 63;
    const int wave = tid >> 6;
    const int m0   = blockIdx.x * 128;

    const unsigned short* Bt = bsel == 0 ? g_W1t
                             : bsel == 1 ? g_Wl1t[0]
                             : bsel == 2 ? g_Wl1t[1]
                             : bsel == 3 ? g_Wl2t[0] : g_Wl2t[1];
    const float* bias = bsel == 0 ? g_b1
                      : bsel == 1 ? g_bl1
                      : bsel == 2 ? g_bl1 + 256 : g_bl2;

    // A staging: 2 threads/row, 64 B each (4 x uint4)
    const int ar   = tid >> 1;
    const int ak   = (tid & 1) << 5;          // element base (32 elems = 64 B)
    const int awb  = (ar << 7) + (ak << 1);   // byte base
    const int aswz = (ar & 7) << 4;
    const size_t arow = (size_t)(m0 + ar) * H + ak;
    // B staging (identical to R3/R5/R7)
    const int nrow = lane >> 3;
    const int kbu  = ((lane & 7) ^ nrow) << 4;

    f32x4 acc[4][8];
    const f32x4 zz = {0.f, 0.f, 0.f, 0.f};
#pragma unroll
    for (int i = 0; i < 4; ++i)
#pragma unroll
        for (int j = 0; j < 8; ++j) acc[i][j] = zz;

    const int fr   = lane & 15;
    const int fg   = lane >> 4;
    const int rowb = (wave >> 1) << 6;   // 0 / 64
    const int colb = (wave & 1) << 7;    // 0 / 128

    for (int kt = 0; kt < 4; ++kt) {
#pragma unroll
        for (int j = 0; j < 8; ++j) {
            const int q = (wave << 3) + j;
            gload_lds16((const char*)Bt + (((size_t)(q << 3) + nrow) << 9)
                            + (kt << 7) + kbu,
                        (char*)Bs + (q << 10));
        }
        {
            const unsigned short* ap = A + arow + (kt << 6);
            uint4 v0 = *(const uint4*)(ap);
            uint4 v1 = *(const uint4*)(ap + 8);
            uint4 v2 = *(const uint4*)(ap + 16);
            uint4 v3 = *(const uint4*)(ap + 24);
            char* asb = (char*)As;
            *(uint4*)(asb + ((awb +  0) ^ aswz)) = v0;
            *(uint4*)(asb + ((awb + 16) ^ aswz)) = v1;
            *(uint4*)(asb + ((awb + 32) ^ aswz)) = v2;
            *(uint4*)(asb + ((awb + 48) ^ aswz)) = v3;
        }
        __syncthreads();   // drains vmcnt (global_load_lds) + lgkmcnt
#pragma unroll
        for (int s = 0; s < 2; ++s) {
            const int kofs = (s << 6) + (fg << 4);
            short8 aF[4];
#pragma unroll
            for (int rg = 0; rg < 4; ++rg) {
                const int r0 = rowb + (rg << 4) + fr;
                aF[rg] = *(const short8*)((const char*)As +
                          ((r0 << 7) + (kofs ^ ((r0 & 7) << 4))));
            }
#pragma unroll
            for (int ct = 0; ct < 8; ++ct) {
                const int cc = colb + (ct << 4) + fr;
                const short8 bF = *(const short8*)((const char*)Bs +
                             ((cc << 7) + (kofs ^ ((cc & 7) << 4))));
#pragma unroll
                for (int rg = 0; rg < 4; ++rg)
                    acc[rg][ct] = __builtin_amdgcn_mfma_f32_16x16x32_bf16(
                        aF[rg], bF, acc[rg][ct], 0, 0, 0);
            }
        }
        __syncthreads();
    }

    const int crow = m0 + rowb + (fg << 2);
    if (MODE == 0) {
#pragma unroll
        for (int ct = 0; ct < 8; ++ct) {
            const int cc = colb + (ct << 4) + fr;
            const float bc = bias[cc];
#pragma unroll
            for (int rg = 0; rg < 4; ++rg) {
#pragma unroll
                for (int r = 0; r < 4; ++r) {
                    float v = acc[rg][ct][r] + bc;
                    if (doRelu) v = fmaxf(v, 0.f);
                    Cb[(size_t)(crow + (rg << 4) + r) * H + cc] = bfbits(v);
                }
            }
        }
    } else {
        const bool is64 = sniff_i64(batch, N_NODES / 2);
        int g[4][5];
#pragma unroll
        for (int rg = 0; rg < 4; ++rg)
#pragma unroll
            for (int r = 0; r < 4; ++r) {
                int gg = ldi(batch, batOff + crow + (rg << 4) + r, is64);
                g[rg][r] = ((unsigned)gg < (unsigned)NGRAPHS) ? gg : 0;
            }
#pragma unroll
        for (int ct = 0; ct < 8; ++ct) {
            const int cc = colb + (ct << 4) + fr;
            const float bc = useBias ? bias[cc] : 0.f;
#pragma unroll
            for (int rg = 0; rg < 4; ++rg) {
                float run = 0.f;
#pragma unroll
                for (int r = 0; r < 4; ++r) {
                    run += acc[rg][ct][r] + bc;
                    if (r == 3 || g[rg][r + 1] != g[rg][r]) {
                        atomicAdd(&Cf[(size_t)g[rg][r] * OUT_C + cc], run);
                        run = 0.f;
                    }
                }
            }
        }
    }
}

// ---------------------------------------------------------------- launcher
extern "C" void kernel_launch(void* const* d_in, const int* in_sizes, int n_in,
                              void* d_out, int out_size, void* d_ws, size_t ws_size,
                              hipStream_t stream) {
    const void *x = nullptr, *eattr = nullptr, *eidx = nullptr, *batch = nullptr;
    const void *W_nh = nullptr, *W1 = nullptr, *We = nullptr, *be = nullptr;
    const void *Wl1 = nullptr, *Wl2 = nullptr, *bl1 = nullptr;
    const void *z256[3] = {nullptr, nullptr, nullptr};
    int nz = 0;
    for (int i = 0; i < n_in; ++i) {
        switch (in_sizes[i]) {
            case N_NODES * NC:     x     = d_in[i]; break;
            case N_EDGES * ED:     eattr = d_in[i]; break;
            case 2 * N_EDGES:      eidx  = d_in[i]; break;
            case N_NODES:          batch = d_in[i]; break;
            case NC * H:           W_nh  = d_in[i]; break;
            case H * H:            W1    = d_in[i]; break;
            case NLAYERS * ED * H: We    = d_in[i]; break;
            case NLAYERS * H:      be    = d_in[i]; break;
            case H * GH:           if (!Wl1) Wl1 = d_in[i]; else Wl2 = d_in[i]; break;
            case GH:               bl1   = d_in[i]; break;
            case H:                if (nz < 3) z256[nz++] = d_in[i]; break;
            default: break;
        }
    }
    const void* b_nh = z256[0];
    const void* b1   = (nz > 1) ? z256[1] : z256[0];
    const void* bl2  = (nz > 2) ? z256[2] : z256[0];
    float* out = (float*)d_out;   // reference output dtype is FLOAT32

    if (!x || !eattr || !eidx || !batch || !W_nh || !W1 || !We || !be ||
        !Wl1 || !Wl2 || !bl1 || !b_nh) {
        fill_f4<<<1024, 256, 0, stream>>>((float4*)out, NGRAPHS * OUT_C / 4, 2.0e6f);
        return;  // sentinel: size-mapping failed
    }

    const size_t NH = (size_t)N_NODES * H;
    const size_t need = NH * 2 + NH * 2;   // hid + hsum, bf16 = 256 MiB
    if (ws_size < need) {
        fill_f4<<<1024, 256, 0, stream>>>((float4*)out, NGRAPHS * OUT_C / 4, 1.0e6f);
        return;  // sentinel: ws too small
    }
    bf16* hid            = (bf16*)d_ws;
    unsigned short* hsum = (unsigned short*)((char*)d_ws + NH * 2);

    // pack weights (transposed, bf16) + biases (fp32) into device globals
    pack_wt<<<256, 256, 0, stream>>>(W1,  H,     0,   0, 0);
    pack_wt<<<256, 256, 0, stream>>>(Wl1, GH,    0,   0, 1);
    pack_wt<<<256, 256, 0, stream>>>(Wl1, GH,    0, 256, 2);
    pack_wt<<<256, 256, 0, stream>>>(Wl2, OUT_C, 0,   0, 3);
    pack_wt<<<256, 256, 0, stream>>>(Wl2, OUT_C, 256, 0, 4);
    pack_bias<<<1, 256, 0, stream>>>(b1, bl1, bl2);

    // ---- build dst-sorted CSR once per launch (device-global storage)
    csr_zero<<<N_NODES / 256, 256, 0, stream>>>();
    hist_dst<<<N_EDGES / 256, 256, 0, stream>>>(eidx);
    scan1<<<N_NODES / 256, 256, 0, stream>>>();
    scan2<<<1, 256, 0, stream>>>();
    scan3<<<N_NODES / 256, 256, 0, stream>>>();
    scatter_e<<<N_EDGES / 256, 256, 0, stream>>>(eidx, eattr);

    node_proj<<<N_NODES / 16, 256, 0, stream>>>(x, W_nh, b_nh, hid);

    for (int l = 0; l < NLAYERS; ++l) {
        // hsum = hid + agg  (wave-pair per node, 2-edge unroll — R7 proven)
        gine_agg<<<N_NODES / 16, 256, 0, stream>>>(
            We, (size_t)l * ED * H, be, (size_t)l * H,
            (const unsigned short*)hid, hsum);
        // hid = relu(hsum @ W1 + b1)
        gemm_mfma<0><<<N_NODES / 128, 256, 0, stream>>>(
            hsum, 0, (unsigned short*)hid, nullptr, nullptr, 0, 1, 1);
    }

    // readout; t0 aliases hsum (dead after last layer GEMM consumed it)
    unsigned short* t0 = hsum;
    fill_f4<<<2048, 256, 0, stream>>>((float4*)out, NGRAPHS * OUT_C / 4, 0.f);
    for (int c = 0; c < 2; ++c) {
        gemm_mfma<0><<<N_NODES / 128, 256, 0, stream>>>(
            (const unsigned short*)hid, 1 + c,
            t0, nullptr, nullptr, 0, 1, 1);
        gemm_mfma<1><<<N_NODES / 128, 256, 0, stream>>>(
            t0, 3 + c,
            nullptr, out, batch, 0, 0, c == 0);
    }
}

// Round 11
// 2305.241 us; speedup vs baseline: 1.1691x; 1.0736x over previous
//
#include <hip/hip_runtime.h>
#include <hip/hip_bf16.h>

#define N_NODES 262144
#define N_EDGES 1048576
#define NC      30
#define ED      13
#define H       256
#define GH      512
#define OUT_C   256
#define NLAYERS 4
#define NGRAPHS 8192

typedef __hip_bfloat16 bf16;
typedef __attribute__((ext_vector_type(8))) short short8;   // 8 bf16 = 4 VGPR
typedef __attribute__((ext_vector_type(4))) float f32x4;

// packed weights: bf16, N-major (Bt[n][k], k contiguous) + fp32 biases
__device__ unsigned short g_W1t[H * H];
__device__ unsigned short g_Wl1t[2][H * H];
__device__ unsigned short g_Wl2t[2][H * H];
__device__ float g_b1[H];
__device__ float g_bl1[GH];
__device__ float g_bl2[OUT_C];
// CSR (device-resident so d_ws only needs hid+hsum = 256 MiB)
__device__ unsigned int g_ssrc[N_EDGES];          // 4 MiB, src ids dst-sorted
__device__ float        g_seat[N_EDGES * 16];     // 64 MiB, eattr dst-sorted, padded
__device__ unsigned int g_rowptr[N_NODES + 1];    // 1 MiB
__device__ unsigned int g_cursor[N_NODES];        // 1 MiB (hist cnt, then cursor)
__device__ unsigned int g_bsum[1024];

__device__ __forceinline__ float hw2f(unsigned short h) {
    return __uint_as_float(((unsigned int)h) << 16);
}
__device__ __forceinline__ float ldf(const void* p, size_t i, bool isbf) {
    return isbf ? hw2f(((const unsigned short*)p)[i]) : ((const float*)p)[i];
}
__device__ __forceinline__ int ldi(const void* p, size_t j, bool is64) {
    return ((const int*)p)[is64 ? 2 * j : j];   // little-endian lo word
}
__device__ __forceinline__ unsigned short bfbits(float f) {
    bf16 b = __float2bfloat16(f);
    return *(unsigned short*)&b;
}
__device__ __forceinline__ float lo16(unsigned int u) { return __uint_as_float(u << 16); }
__device__ __forceinline__ float hi16(unsigned int u) { return __uint_as_float(u & 0xFFFF0000u); }
__device__ __forceinline__ unsigned int pk2(float a, float b) {
    return (unsigned int)bfbits(a) | ((unsigned int)bfbits(b) << 16);
}
// float width sniff: even halfwords. bf16 data -> plausible exponents.
__device__ __forceinline__ bool sniff_bf16(const void* xv) {
    const unsigned short* q = (const unsigned short*)xv;
    int c = 0;
    for (int i = 0; i < 32; ++i) {
        unsigned short h = q[2 * i];
        int e = (h >> 7) & 0xFF;
        c += (h == 0 || (e >= 97 && e <= 141)) ? 1 : 0;
    }
    return c >= 20;
}
// int width sniff: odd 32-bit words all zero <=> int64 (values < 2^31).
__device__ __forceinline__ bool sniff_i64(const void* pv, size_t baseWord) {
    const unsigned int* q = (const unsigned int*)pv;
    int z = 0;
    for (int i = 0; i < 32; ++i) z += (q[baseWord + 2 * i + 1] == 0) ? 1 : 0;
    return z >= 20;
}
// async global->LDS, 16B per lane; dst is wave-uniform base + lane*16
__device__ __forceinline__ void gload_lds16(const void* g, void* l) {
    __builtin_amdgcn_global_load_lds(
        (const __attribute__((address_space(1))) unsigned int*)g,
        (__attribute__((address_space(3))) unsigned int*)l, 16, 0, 0);
}

// ---------------------------------------------------------------- fills
__global__ __launch_bounds__(256) void fill_f4(float4* p, int n4, float val) {
    int i = blockIdx.x * 256 + threadIdx.x;
    int stride = gridDim.x * 256;
    float4 z = make_float4(val, val, val, val);
    for (; i < n4; i += stride) p[i] = z;
}

// ---------------------------------------------------- weight / bias packers
// out[n][k] = in[k0+k][n0+n]  (transpose + bf16-normalize), 256x256 chunk
__global__ __launch_bounds__(256) void pack_wt(const void* __restrict__ in,
        int ldin, int k0, int n0, int which) {
    const bool isbf = sniff_bf16(in);
    unsigned short* outp = which == 0 ? g_W1t
                         : which == 1 ? g_Wl1t[0]
                         : which == 2 ? g_Wl1t[1]
                         : which == 3 ? g_Wl2t[0] : g_Wl2t[1];
    const int n = blockIdx.x, k = threadIdx.x;
    outp[(n << 8) + k] = bfbits(ldf(in, (size_t)(k0 + k) * ldin + n0 + n, isbf));
}
__global__ __launch_bounds__(256) void pack_bias(const void* b1, const void* bl1,
                                                 const void* bl2) {
    const int t = threadIdx.x;
    const bool s1 = sniff_bf16(b1), s2 = sniff_bf16(bl1), s3 = sniff_bf16(bl2);
    g_b1[t]        = ldf(b1,  t,       s1);
    g_bl1[t]       = ldf(bl1, t,       s2);
    g_bl1[t + 256] = ldf(bl1, t + 256, s2);
    g_bl2[t]       = ldf(bl2, t,       s3);
}

// ------------------------------------------------------------- CSR build
__global__ __launch_bounds__(256) void csr_zero() {
    g_cursor[blockIdx.x * 256 + threadIdx.x] = 0u;
}
__global__ __launch_bounds__(256) void hist_dst(const void* __restrict__ eidx) {
    const bool is64 = sniff_i64(eidx, 0);
    const int e = blockIdx.x * 256 + threadIdx.x;
    int dst = ldi(eidx, (size_t)N_EDGES + e, is64);
    if ((unsigned)dst >= (unsigned)N_NODES) dst = 0;
    atomicAdd(&g_cursor[dst], 1u);
}
__global__ __launch_bounds__(256) void scan1() {
    __shared__ unsigned int sh[256];
    const int tid = threadIdx.x;
    sh[tid] = g_cursor[blockIdx.x * 256 + tid];
    __syncthreads();
    for (int s = 128; s > 0; s >>= 1) {
        if (tid < s) sh[tid] += sh[tid + s];
        __syncthreads();
    }
    if (tid == 0) g_bsum[blockIdx.x] = sh[0];
}
__global__ __launch_bounds__(256) void scan2() {
    __shared__ unsigned int sh[1024];
    const int tid = threadIdx.x;
    for (int j = tid; j < 1024; j += 256) sh[j] = g_bsum[j];
    __syncthreads();
    if (tid == 0) {
        unsigned int run = 0;
        for (int j = 0; j < 1024; ++j) { unsigned int t = sh[j]; sh[j] = run; run += t; }
    }
    __syncthreads();
    for (int j = tid; j < 1024; j += 256) g_bsum[j] = sh[j];
}
__global__ __launch_bounds__(256) void scan3() {
    __shared__ unsigned int sh[256];
    const int tid = threadIdx.x;
    const int i = blockIdx.x * 256 + tid;
    const unsigned int v = g_cursor[i];
    sh[tid] = v;
    __syncthreads();
    for (int ofs = 1; ofs < 256; ofs <<= 1) {
        unsigned int t = (tid >= ofs) ? sh[tid - ofs] : 0u;
        __syncthreads();
        sh[tid] += t;
        __syncthreads();
    }
    const unsigned int excl = sh[tid] - v + g_bsum[blockIdx.x];
    g_rowptr[i] = excl;
    g_cursor[i] = excl;
    if (i == N_NODES - 1) g_rowptr[N_NODES] = excl + v;
}
// scatter src ids and edge_attr rows (fp32, padded to 16) into dst order
__global__ __launch_bounds__(256) void scatter_e(
        const void* __restrict__ eidx, const void* __restrict__ eattr) {
    const bool is64 = sniff_i64(eidx, 0);
    const bool isbf = sniff_bf16(eattr);
    const int e = blockIdx.x * 256 + threadIdx.x;
    int src = ldi(eidx, e, is64);
    int dst = ldi(eidx, (size_t)N_EDGES + e, is64);
    if ((unsigned)src >= (unsigned)N_NODES) src = 0;
    if ((unsigned)dst >= (unsigned)N_NODES) dst = 0;
    unsigned int pos = atomicAdd(&g_cursor[dst], 1u);
    if (pos >= (unsigned)N_EDGES) return;   // safety
    g_ssrc[pos] = (unsigned int)src;
    float a[16];
#pragma unroll
    for (int k = 0; k < ED; ++k) a[k] = ldf(eattr, (size_t)e * ED + k, isbf);
    a[13] = 0.f; a[14] = 0.f; a[15] = 0.f;
    float* so = g_seat + (size_t)pos * 16;
#pragma unroll
    for (int k = 0; k < 4; ++k)
        *(float4*)(so + 4 * k) = *(float4*)(a + 4 * k);
}

// ------------------------------------------------- hid = x @ W_nh + b_nh
__global__ __launch_bounds__(256) void node_proj(
        const void* __restrict__ x, const void* __restrict__ W,
        const void* __restrict__ b, bf16* __restrict__ hid) {
    const bool isbf = sniff_bf16(x);
    __shared__ float xs[16 * NC];
    const int m0 = blockIdx.x * 16;
    for (int i = threadIdx.x; i < 16 * NC; i += 256)
        xs[i] = ldf(x, (size_t)m0 * NC + i, isbf);
    __syncthreads();
    const int col = threadIdx.x;
    float w[NC];
#pragma unroll
    for (int k = 0; k < NC; ++k) w[k] = ldf(W, (size_t)k * H + col, isbf);
    const float bias = ldf(b, col, isbf);
#pragma unroll 4
    for (int r = 0; r < 16; ++r) {
        float acc = bias;
#pragma unroll
        for (int k = 0; k < NC; ++k) acc += xs[r * NC + k] * w[k];
        hid[(size_t)(m0 + r) * H + col] = __float2bfloat16(acc);
    }
}

// --------------------------------------------- CSR aggregation (no atomics)
// (exact R7/R10 kernel — 267 µs proven; register experiments closed R9/R10)
__global__ __launch_bounds__(256, 4) void gine_agg(
        const void* __restrict__ We, size_t weOff,
        const void* __restrict__ be, size_t beOff,
        const unsigned short* __restrict__ hid,
        unsigned short* __restrict__ hsum) {
    const bool isbf = sniff_bf16(We);
    const int lane = threadIdx.x & 63;
    const int wave = threadIdx.x >> 6;
    const int wh   = wave & 1;       // which 128-col half
    const int wp   = wave >> 1;      // wave-pair id within block
    const int c0 = 128 * wh + 2 * lane;
    float w0[ED], w1[ED];
#pragma unroll
    for (int k = 0; k < ED; ++k) {
        const size_t o = weOff + (size_t)k * H;
        w0[k] = ldf(We, o + c0,     isbf);
        w1[k] = ldf(We, o + c0 + 1, isbf);
    }
    const float bb0 = ldf(be, beOff + c0,     isbf);
    const float bb1 = ldf(be, beOff + c0 + 1, isbf);

    const int nbase = blockIdx.x * 16 + wp * 8;
    for (int j = 0; j < 8; ++j) {
        const int node = nbase + j;
        const unsigned int r0 = __builtin_amdgcn_readfirstlane(g_rowptr[node]);
        const unsigned int r1 = __builtin_amdgcn_readfirstlane(g_rowptr[node + 1]);
        const unsigned int hu = *(const unsigned int*)(hid + (size_t)node * H + c0);
        float a0 = lo16(hu);
        float a1 = hi16(hu);
        unsigned int e = r0;
        for (; e + 2 <= r1; e += 2) {
            const unsigned int sA = __builtin_amdgcn_readfirstlane(g_ssrc[e]);
            const unsigned int sB = __builtin_amdgcn_readfirstlane(g_ssrc[e + 1]);
            const float* pA = g_seat + (size_t)e * 16;
            const float* pB = pA + 16;
            const unsigned int hA = *(const unsigned int*)(hid + (size_t)sA * H + c0);
            const unsigned int hB = *(const unsigned int*)(hid + (size_t)sB * H + c0);
            const float4 fA0 = *(const float4*)(pA);
            const float4 fA1 = *(const float4*)(pA + 4);
            const float4 fA2 = *(const float4*)(pA + 8);
            const float  fAc = pA[12];
            const float4 fB0 = *(const float4*)(pB);
            const float4 fB1 = *(const float4*)(pB + 4);
            const float4 fB2 = *(const float4*)(pB + 8);
            const float  fBc = pB[12];
            const float afA[ED] = {fA0.x, fA0.y, fA0.z, fA0.w, fA1.x, fA1.y,
                                   fA1.z, fA1.w, fA2.x, fA2.y, fA2.z, fA2.w, fAc};
            const float afB[ED] = {fB0.x, fB0.y, fB0.z, fB0.w, fB1.x, fB1.y,
                                   fB1.z, fB1.w, fB2.x, fB2.y, fB2.z, fB2.w, fBc};
            float mA0 = bb0, mA1 = bb1, mB0 = bb0, mB1 = bb1;
#pragma unroll
            for (int k = 0; k < ED; ++k) {
                mA0 += afA[k] * w0[k];
                mA1 += afA[k] * w1[k];
                mB0 += afB[k] * w0[k];
                mB1 += afB[k] * w1[k];
            }
            a0 += fmaxf(mA0 + lo16(hA), 0.f) + fmaxf(mB0 + lo16(hB), 0.f);
            a1 += fmaxf(mA1 + hi16(hA), 0.f) + fmaxf(mB1 + hi16(hB), 0.f);
        }
        if (e < r1) {   // odd tail
            const unsigned int s = __builtin_amdgcn_readfirstlane(g_ssrc[e]);
            const float* sp = g_seat + (size_t)e * 16;
            const unsigned int hs = *(const unsigned int*)(hid + (size_t)s * H + c0);
            const float4 f0 = *(const float4*)(sp);
            const float4 f1 = *(const float4*)(sp + 4);
            const float4 f2 = *(const float4*)(sp + 8);
            const float  fc = sp[12];
            const float af[ED] = {f0.x, f0.y, f0.z, f0.w, f1.x, f1.y, f1.z,
                                  f1.w, f2.x, f2.y, f2.z, f2.w, fc};
            float m0 = bb0, m1 = bb1;
#pragma unroll
            for (int k = 0; k < ED; ++k) {
                m0 += af[k] * w0[k];
                m1 += af[k] * w1[k];
            }
            a0 += fmaxf(m0 + lo16(hs), 0.f);
            a1 += fmaxf(m1 + hi16(hs), 0.f);
        }
        *(unsigned int*)(hsum + (size_t)node * H + c0) = pk2(a0, a1);
    }
}

// ------------------------------------------------- 2-phase MFMA GEMM (T3-lite)
// BM=64 BN=256 BK=64 (R7-proven geometry) + DOUBLE-BUFFERED staging:
// per iteration, ISSUE next tile's global_load_lds (A and B, both async,
// both with pre-inverse-swizzled per-lane source + linear LDS dest), then
// ds_read+MFMA the current buffer, then one barrier. The barrier's vmcnt(0)
// drain now waits on loads that had a full compute phase in flight — vs R7's
// stage->drain->compute which exposed the full HBM/L2 latency 4x per block
// (the measured 130 µs vs 41 µs traffic floor; m233's 72% stall pattern).
// LDS 80 KB -> 2 blocks/CU; within-block pipelining replaces the lost TLP.
// MODE 0: Cb = bf16(act(..)).  MODE 1: fp32 atomicAdd pooled by batch[].
template <int MODE>
__global__ __launch_bounds__(256, 2) void gemm_mfma(
        const unsigned short* __restrict__ A, int bsel,
        unsigned short* __restrict__ Cb, float* __restrict__ Cf,
        const void* __restrict__ batch, size_t batOff, int doRelu, int useBias) {
    __shared__ unsigned short As[2][64 * 64];    // 2 x 8 KB, swizzled
    __shared__ unsigned short Bs[2][256 * 64];   // 2 x 32 KB, [n][k], swizzled
    const int tid  = threadIdx.x;
    const int lane = tid & 63;
    const int wave = tid >> 6;
    const int m0   = blockIdx.x * 64;

    const unsigned short* Bt = bsel == 0 ? g_W1t
                             : bsel == 1 ? g_Wl1t[0]
                             : bsel == 2 ? g_Wl1t[1]
                             : bsel == 3 ? g_Wl2t[0] : g_Wl2t[1];
    const float* bias = bsel == 0 ? g_b1
                      : bsel == 1 ? g_bl1
                      : bsel == 2 ? g_bl1 + 256 : g_bl2;

    // B staging: 8 x 1KB chunks per wave; chunk q = 8 rows x 128B.
    const int nrow = lane >> 3;                  // row within chunk (0..7)
    const int kbu  = ((lane & 7) ^ nrow) << 4;   // inverse-swizzled src slot
    // A staging: 2 x 1KB chunks per wave; same 8-row x 128B geometry.

    f32x4 acc0[8], acc1[8];
    const f32x4 zz = {0.f, 0.f, 0.f, 0.f};
#pragma unroll
    for (int i = 0; i < 8; ++i) { acc0[i] = zz; acc1[i] = zz; }

    const int fr   = lane & 15;
    const int fg   = lane >> 4;
    const int rowb = (wave >> 1) << 5;   // 0 / 32
    const int colb = (wave & 1) << 7;    // 0 / 128

    // stage tile kt into buffer hb (all async; no reg round-trip)
    auto STAGE = [&](int hb, int kt) {
#pragma unroll
        for (int j = 0; j < 8; ++j) {           // B: 32 KB
            const int q = (wave << 3) + j;
            gload_lds16((const char*)Bt + (((size_t)(q << 3) + nrow) << 9)
                            + (kt << 7) + kbu,
                        (char*)Bs[hb] + (q << 10));
        }
#pragma unroll
        for (int j = 0; j < 2; ++j) {           // A: 8 KB
            const int q = (wave << 1) + j;
            gload_lds16((const char*)A + (((size_t)m0 + (q << 3) + nrow) << 9)
                            + (kt << 7) + kbu,
                        (char*)As[hb] + (q << 10));
        }
    };

    STAGE(0, 0);
    __syncthreads();                            // prologue drain

    for (int kt = 0; kt < 4; ++kt) {
        const int cur = kt & 1;
        if (kt < 3) STAGE(cur ^ 1, kt + 1);     // issue next tile FIRST
        const char* asb = (const char*)As[cur];
        const char* bsb = (const char*)Bs[cur];
#pragma unroll
        for (int s = 0; s < 2; ++s) {
            const int kofs = (s << 6) + (fg << 4);
            const int r0 = rowb + fr;
            short8 aF0 = *(const short8*)(asb +
                          ((r0 << 7) + (kofs ^ ((r0 & 7) << 4))));
            short8 aF1 = *(const short8*)(asb +
                          (((r0 + 16) << 7) + (kofs ^ ((r0 & 7) << 4))));
#pragma unroll
            for (int ct = 0; ct < 8; ++ct) {
                const int cc = colb + (ct << 4) + fr;
                short8 bF = *(const short8*)(bsb +
                             ((cc << 7) + (kofs ^ ((cc & 7) << 4))));
                acc0[ct] = __builtin_amdgcn_mfma_f32_16x16x32_bf16(aF0, bF, acc0[ct], 0, 0, 0);
                acc1[ct] = __builtin_amdgcn_mfma_f32_16x16x32_bf16(aF1, bF, acc1[ct], 0, 0, 0);
            }
        }
        __syncthreads();   // one drain per tile; next-tile loads flew under compute
    }

    const int crow = m0 + rowb + (fg << 2);
    if (MODE == 0) {
#pragma unroll
        for (int ct = 0; ct < 8; ++ct) {
            const int cc = colb + (ct << 4) + fr;
            const float bc = bias[cc];
#pragma unroll
            for (int r = 0; r < 4; ++r) {
                float v0 = acc0[ct][r] + bc;
                float v1 = acc1[ct][r] + bc;
                if (doRelu) { v0 = fmaxf(v0, 0.f); v1 = fmaxf(v1, 0.f); }
                Cb[(size_t)(crow + r) * H + cc]      = bfbits(v0);
                Cb[(size_t)(crow + 16 + r) * H + cc] = bfbits(v1);
            }
        }
    } else {
        const bool is64 = sniff_i64(batch, N_NODES / 2);
        int ga[5], gb[5];
#pragma unroll
        for (int r = 0; r < 4; ++r) {
            int g0 = ldi(batch, batOff + crow + r, is64);
            int g1 = ldi(batch, batOff + crow + 16 + r, is64);
            ga[r] = ((unsigned)g0 < (unsigned)NGRAPHS) ? g0 : 0;
            gb[r] = ((unsigned)g1 < (unsigned)NGRAPHS) ? g1 : 0;
        }
#pragma unroll
        for (int ct = 0; ct < 8; ++ct) {
            const int cc = colb + (ct << 4) + fr;
            const float bc = useBias ? bias[cc] : 0.f;
            float run0 = 0.f, run1 = 0.f;
#pragma unroll
            for (int r = 0; r < 4; ++r) {
                run0 += acc0[ct][r] + bc;
                if (r == 3 || ga[r + 1] != ga[r]) {
                    atomicAdd(&Cf[(size_t)ga[r] * OUT_C + cc], run0); run0 = 0.f;
                }
                run1 += acc1[ct][r] + bc;
                if (r == 3 || gb[r + 1] != gb[r]) {
                    atomicAdd(&Cf[(size_t)gb[r] * OUT_C + cc], run1); run1 = 0.f;
                }
            }
        }
    }
}

// ---------------------------------------------------------------- launcher
extern "C" void kernel_launch(void* const* d_in, const int* in_sizes, int n_in,
                              void* d_out, int out_size, void* d_ws, size_t ws_size,
                              hipStream_t stream) {
    const void *x = nullptr, *eattr = nullptr, *eidx = nullptr, *batch = nullptr;
    const void *W_nh = nullptr, *W1 = nullptr, *We = nullptr, *be = nullptr;
    const void *Wl1 = nullptr, *Wl2 = nullptr, *bl1 = nullptr;
    const void *z256[3] = {nullptr, nullptr, nullptr};
    int nz = 0;
    for (int i = 0; i < n_in; ++i) {
        switch (in_sizes[i]) {
            case N_NODES * NC:     x     = d_in[i]; break;
            case N_EDGES * ED:     eattr = d_in[i]; break;
            case 2 * N_EDGES:      eidx  = d_in[i]; break;
            case N_NODES:          batch = d_in[i]; break;
            case NC * H:           W_nh  = d_in[i]; break;
            case H * H:            W1    = d_in[i]; break;
            case NLAYERS * ED * H: We    = d_in[i]; break;
            case NLAYERS * H:      be    = d_in[i]; break;
            case H * GH:           if (!Wl1) Wl1 = d_in[i]; else Wl2 = d_in[i]; break;
            case GH:               bl1   = d_in[i]; break;
            case H:                if (nz < 3) z256[nz++] = d_in[i]; break;
            default: break;
        }
    }
    const void* b_nh = z256[0];
    const void* b1   = (nz > 1) ? z256[1] : z256[0];
    const void* bl2  = (nz > 2) ? z256[2] : z256[0];
    float* out = (float*)d_out;   // reference output dtype is FLOAT32

    if (!x || !eattr || !eidx || !batch || !W_nh || !W1 || !We || !be ||
        !Wl1 || !Wl2 || !bl1 || !b_nh) {
        fill_f4<<<1024, 256, 0, stream>>>((float4*)out, NGRAPHS * OUT_C / 4, 2.0e6f);
        return;  // sentinel: size-mapping failed
    }

    const size_t NH = (size_t)N_NODES * H;
    const size_t need = NH * 2 + NH * 2;   // hid + hsum, bf16 = 256 MiB
    if (ws_size < need) {
        fill_f4<<<1024, 256, 0, stream>>>((float4*)out, NGRAPHS * OUT_C / 4, 1.0e6f);
        return;  // sentinel: ws too small
    }
    bf16* hid            = (bf16*)d_ws;
    unsigned short* hsum = (unsigned short*)((char*)d_ws + NH * 2);

    // pack weights (transposed, bf16) + biases (fp32) into device globals
    pack_wt<<<256, 256, 0, stream>>>(W1,  H,     0,   0, 0);
    pack_wt<<<256, 256, 0, stream>>>(Wl1, GH,    0,   0, 1);
    pack_wt<<<256, 256, 0, stream>>>(Wl1, GH,    0, 256, 2);
    pack_wt<<<256, 256, 0, stream>>>(Wl2, OUT_C, 0,   0, 3);
    pack_wt<<<256, 256, 0, stream>>>(Wl2, OUT_C, 256, 0, 4);
    pack_bias<<<1, 256, 0, stream>>>(b1, bl1, bl2);

    // ---- build dst-sorted CSR once per launch (device-global storage)
    csr_zero<<<N_NODES / 256, 256, 0, stream>>>();
    hist_dst<<<N_EDGES / 256, 256, 0, stream>>>(eidx);
    scan1<<<N_NODES / 256, 256, 0, stream>>>();
    scan2<<<1, 256, 0, stream>>>();
    scan3<<<N_NODES / 256, 256, 0, stream>>>();
    scatter_e<<<N_EDGES / 256, 256, 0, stream>>>(eidx, eattr);

    node_proj<<<N_NODES / 16, 256, 0, stream>>>(x, W_nh, b_nh, hid);

    for (int l = 0; l < NLAYERS; ++l) {
        // hsum = hid + agg  (wave-pair per node, 2-edge unroll — proven)
        gine_agg<<<N_NODES / 16, 256, 0, stream>>>(
            We, (size_t)l * ED * H, be, (size_t)l * H,
            (const unsigned short*)hid, hsum);
        // hid = relu(hsum @ W1 + b1)
        gemm_mfma<0><<<N_NODES / 64, 256, 0, stream>>>(
            hsum, 0, (unsigned short*)hid, nullptr, nullptr, 0, 1, 1);
    }

    // readout; t0 aliases hsum (dead after last layer GEMM consumed it)
    unsigned short* t0 = hsum;
    fill_f4<<<2048, 256, 0, stream>>>((float4*)out, NGRAPHS * OUT_C / 4, 0.f);
    for (int c = 0; c < 2; ++c) {
        gemm_mfma<0><<<N_NODES / 64, 256, 0, stream>>>(
            (const unsigned short*)hid, 1 + c,
            t0, nullptr, nullptr, 0, 1, 1);
        gemm_mfma<1><<<N_NODES / 64, 256, 0, stream>>>(
            t0, 3 + c,
            nullptr, out, batch, 0, 0, c == 0);
    }
}

// Round 12
// 2273.494 us; speedup vs baseline: 1.1854x; 1.0140x over previous
//
#include <hip/hip_runtime.h>
#include <hip/hip_bf16.h>

#define N_NODES 262144
#define N_EDGES 1048576
#define NC      30
#define ED      13
#define H       256
#define GH      512
#define OUT_C   256
#define NLAYERS 4
#define NGRAPHS 8192

typedef __hip_bfloat16 bf16;
typedef __attribute__((ext_vector_type(8))) short short8;   // 8 bf16 = 4 VGPR
typedef __attribute__((ext_vector_type(4))) float f32x4;

// packed weights: bf16, N-major (Bt[n][k], k contiguous) + fp32 biases
__device__ unsigned short g_W1t[H * H];
__device__ unsigned short g_Wl1t[2][H * H];
__device__ unsigned short g_Wl2t[2][H * H];
__device__ float g_b1[H];
__device__ float g_bl1[GH];
__device__ float g_bl2[OUT_C];
// CSR (device-resident so d_ws only needs hid+hsum = 256 MiB)
__device__ unsigned int g_ssrc[N_EDGES];          // 4 MiB, src ids dst-sorted
__device__ float        g_seat[N_EDGES * 16];     // 64 MiB, eattr dst-sorted, padded
__device__ unsigned int g_rowptr[N_NODES + 1];    // 1 MiB
__device__ unsigned int g_cursor[N_NODES];        // 1 MiB (hist cnt, then cursor)
__device__ unsigned int g_bsum[1024];
// pooled-readout state: P[g] = sum of t1 rows of graph g; cntf[g] = #nodes
__device__ float g_P[NGRAPHS * GH];               // 16 MiB
__device__ float g_cntf[NGRAPHS];

__device__ __forceinline__ float hw2f(unsigned short h) {
    return __uint_as_float(((unsigned int)h) << 16);
}
__device__ __forceinline__ float ldf(const void* p, size_t i, bool isbf) {
    return isbf ? hw2f(((const unsigned short*)p)[i]) : ((const float*)p)[i];
}
__device__ __forceinline__ int ldi(const void* p, size_t j, bool is64) {
    return ((const int*)p)[is64 ? 2 * j : j];   // little-endian lo word
}
__device__ __forceinline__ unsigned short bfbits(float f) {
    bf16 b = __float2bfloat16(f);
    return *(unsigned short*)&b;
}
__device__ __forceinline__ float lo16(unsigned int u) { return __uint_as_float(u << 16); }
__device__ __forceinline__ float hi16(unsigned int u) { return __uint_as_float(u & 0xFFFF0000u); }
__device__ __forceinline__ unsigned int pk2(float a, float b) {
    return (unsigned int)bfbits(a) | ((unsigned int)bfbits(b) << 16);
}
// float width sniff: even halfwords. bf16 data -> plausible exponents.
__device__ __forceinline__ bool sniff_bf16(const void* xv) {
    const unsigned short* q = (const unsigned short*)xv;
    int c = 0;
    for (int i = 0; i < 32; ++i) {
        unsigned short h = q[2 * i];
        int e = (h >> 7) & 0xFF;
        c += (h == 0 || (e >= 97 && e <= 141)) ? 1 : 0;
    }
    return c >= 20;
}
// int width sniff: odd 32-bit words all zero <=> int64 (values < 2^31).
__device__ __forceinline__ bool sniff_i64(const void* pv, size_t baseWord) {
    const unsigned int* q = (const unsigned int*)pv;
    int z = 0;
    for (int i = 0; i < 32; ++i) z += (q[baseWord + 2 * i + 1] == 0) ? 1 : 0;
    return z >= 20;
}
// async global->LDS, 16B per lane; dst is wave-uniform base + lane*16
__device__ __forceinline__ void gload_lds16(const void* g, void* l) {
    __builtin_amdgcn_global_load_lds(
        (const __attribute__((address_space(1))) unsigned int*)g,
        (__attribute__((address_space(3))) unsigned int*)l, 16, 0, 0);
}

// ---------------------------------------------------------------- fills
__global__ __launch_bounds__(256) void fill_f4(float4* p, int n4, float val) {
    int i = blockIdx.x * 256 + threadIdx.x;
    int stride = gridDim.x * 256;
    float4 z = make_float4(val, val, val, val);
    for (; i < n4; i += stride) p[i] = z;
}
__global__ __launch_bounds__(256) void pzero() {       // grid 4096
    ((float4*)g_P)[blockIdx.x * 256 + threadIdx.x] = make_float4(0.f, 0.f, 0.f, 0.f);
}
__global__ __launch_bounds__(256) void czero() {       // grid 32
    g_cntf[blockIdx.x * 256 + threadIdx.x] = 0.f;
}
__global__ __launch_bounds__(256) void hist_b(const void* __restrict__ batch) {
    const bool is64 = sniff_i64(batch, N_NODES / 2);
    const int n = blockIdx.x * 256 + threadIdx.x;
    int g = ldi(batch, (size_t)n, is64);
    if ((unsigned)g >= (unsigned)NGRAPHS) g = 0;
    atomicAdd(&g_cntf[g], 1.0f);
}

// ---------------------------------------------------- weight / bias packers
// out[n][k] = in[k0+k][n0+n]  (transpose + bf16-normalize), 256x256 chunk
__global__ __launch_bounds__(256) void pack_wt(const void* __restrict__ in,
        int ldin, int k0, int n0, int which) {
    const bool isbf = sniff_bf16(in);
    unsigned short* outp = which == 0 ? g_W1t
                         : which == 1 ? g_Wl1t[0]
                         : which == 2 ? g_Wl1t[1]
                         : which == 3 ? g_Wl2t[0] : g_Wl2t[1];
    const int n = blockIdx.x, k = threadIdx.x;
    outp[(n << 8) + k] = bfbits(ldf(in, (size_t)(k0 + k) * ldin + n0 + n, isbf));
}
__global__ __launch_bounds__(256) void pack_bias(const void* b1, const void* bl1,
                                                 const void* bl2) {
    const int t = threadIdx.x;
    const bool s1 = sniff_bf16(b1), s2 = sniff_bf16(bl1), s3 = sniff_bf16(bl2);
    g_b1[t]        = ldf(b1,  t,       s1);
    g_bl1[t]       = ldf(bl1, t,       s2);
    g_bl1[t + 256] = ldf(bl1, t + 256, s2);
    g_bl2[t]       = ldf(bl2, t,       s3);
}

// ------------------------------------------------------------- CSR build
__global__ __launch_bounds__(256) void csr_zero() {
    g_cursor[blockIdx.x * 256 + threadIdx.x] = 0u;
}
__global__ __launch_bounds__(256) void hist_dst(const void* __restrict__ eidx) {
    const bool is64 = sniff_i64(eidx, 0);
    const int e = blockIdx.x * 256 + threadIdx.x;
    int dst = ldi(eidx, (size_t)N_EDGES + e, is64);
    if ((unsigned)dst >= (unsigned)N_NODES) dst = 0;
    atomicAdd(&g_cursor[dst], 1u);
}
__global__ __launch_bounds__(256) void scan1() {
    __shared__ unsigned int sh[256];
    const int tid = threadIdx.x;
    sh[tid] = g_cursor[blockIdx.x * 256 + tid];
    __syncthreads();
    for (int s = 128; s > 0; s >>= 1) {
        if (tid < s) sh[tid] += sh[tid + s];
        __syncthreads();
    }
    if (tid == 0) g_bsum[blockIdx.x] = sh[0];
}
__global__ __launch_bounds__(256) void scan2() {
    __shared__ unsigned int sh[1024];
    const int tid = threadIdx.x;
    for (int j = tid; j < 1024; j += 256) sh[j] = g_bsum[j];
    __syncthreads();
    if (tid == 0) {
        unsigned int run = 0;
        for (int j = 0; j < 1024; ++j) { unsigned int t = sh[j]; sh[j] = run; run += t; }
    }
    __syncthreads();
    for (int j = tid; j < 1024; j += 256) g_bsum[j] = sh[j];
}
__global__ __launch_bounds__(256) void scan3() {
    __shared__ unsigned int sh[256];
    const int tid = threadIdx.x;
    const int i = blockIdx.x * 256 + tid;
    const unsigned int v = g_cursor[i];
    sh[tid] = v;
    __syncthreads();
    for (int ofs = 1; ofs < 256; ofs <<= 1) {
        unsigned int t = (tid >= ofs) ? sh[tid - ofs] : 0u;
        __syncthreads();
        sh[tid] += t;
        __syncthreads();
    }
    const unsigned int excl = sh[tid] - v + g_bsum[blockIdx.x];
    g_rowptr[i] = excl;
    g_cursor[i] = excl;
    if (i == N_NODES - 1) g_rowptr[N_NODES] = excl + v;
}
// scatter src ids and edge_attr rows (fp32, padded to 16) into dst order
__global__ __launch_bounds__(256) void scatter_e(
        const void* __restrict__ eidx, const void* __restrict__ eattr) {
    const bool is64 = sniff_i64(eidx, 0);
    const bool isbf = sniff_bf16(eattr);
    const int e = blockIdx.x * 256 + threadIdx.x;
    int src = ldi(eidx, e, is64);
    int dst = ldi(eidx, (size_t)N_EDGES + e, is64);
    if ((unsigned)src >= (unsigned)N_NODES) src = 0;
    if ((unsigned)dst >= (unsigned)N_NODES) dst = 0;
    unsigned int pos = atomicAdd(&g_cursor[dst], 1u);
    if (pos >= (unsigned)N_EDGES) return;   // safety
    g_ssrc[pos] = (unsigned int)src;
    float a[16];
#pragma unroll
    for (int k = 0; k < ED; ++k) a[k] = ldf(eattr, (size_t)e * ED + k, isbf);
    a[13] = 0.f; a[14] = 0.f; a[15] = 0.f;
    float* so = g_seat + (size_t)pos * 16;
#pragma unroll
    for (int k = 0; k < 4; ++k)
        *(float4*)(so + 4 * k) = *(float4*)(a + 4 * k);
}

// ------------------------------------------------- hid = x @ W_nh + b_nh
__global__ __launch_bounds__(256) void node_proj(
        const void* __restrict__ x, const void* __restrict__ W,
        const void* __restrict__ b, bf16* __restrict__ hid) {
    const bool isbf = sniff_bf16(x);
    __shared__ float xs[16 * NC];
    const int m0 = blockIdx.x * 16;
    for (int i = threadIdx.x; i < 16 * NC; i += 256)
        xs[i] = ldf(x, (size_t)m0 * NC + i, isbf);
    __syncthreads();
    const int col = threadIdx.x;
    float w[NC];
#pragma unroll
    for (int k = 0; k < NC; ++k) w[k] = ldf(W, (size_t)k * H + col, isbf);
    const float bias = ldf(b, col, isbf);
#pragma unroll 4
    for (int r = 0; r < 16; ++r) {
        float acc = bias;
#pragma unroll
        for (int k = 0; k < NC; ++k) acc += xs[r * NC + k] * w[k];
        hid[(size_t)(m0 + r) * H + col] = __float2bfloat16(acc);
    }
}

// --------------------------------------------- CSR aggregation (no atomics)
// (exact R7/R10 kernel — 267-272 µs proven; register experiments closed)
__global__ __launch_bounds__(256, 4) void gine_agg(
        const void* __restrict__ We, size_t weOff,
        const void* __restrict__ be, size_t beOff,
        const unsigned short* __restrict__ hid,
        unsigned short* __restrict__ hsum) {
    const bool isbf = sniff_bf16(We);
    const int lane = threadIdx.x & 63;
    const int wave = threadIdx.x >> 6;
    const int wh   = wave & 1;       // which 128-col half
    const int wp   = wave >> 1;      // wave-pair id within block
    const int c0 = 128 * wh + 2 * lane;
    float w0[ED], w1[ED];
#pragma unroll
    for (int k = 0; k < ED; ++k) {
        const size_t o = weOff + (size_t)k * H;
        w0[k] = ldf(We, o + c0,     isbf);
        w1[k] = ldf(We, o + c0 + 1, isbf);
    }
    const float bb0 = ldf(be, beOff + c0,     isbf);
    const float bb1 = ldf(be, beOff + c0 + 1, isbf);

    const int nbase = blockIdx.x * 16 + wp * 8;
    for (int j = 0; j < 8; ++j) {
        const int node = nbase + j;
        const unsigned int r0 = __builtin_amdgcn_readfirstlane(g_rowptr[node]);
        const unsigned int r1 = __builtin_amdgcn_readfirstlane(g_rowptr[node + 1]);
        const unsigned int hu = *(const unsigned int*)(hid + (size_t)node * H + c0);
        float a0 = lo16(hu);
        float a1 = hi16(hu);
        unsigned int e = r0;
        for (; e + 2 <= r1; e += 2) {
            const unsigned int sA = __builtin_amdgcn_readfirstlane(g_ssrc[e]);
            const unsigned int sB = __builtin_amdgcn_readfirstlane(g_ssrc[e + 1]);
            const float* pA = g_seat + (size_t)e * 16;
            const float* pB = pA + 16;
            const unsigned int hA = *(const unsigned int*)(hid + (size_t)sA * H + c0);
            const unsigned int hB = *(const unsigned int*)(hid + (size_t)sB * H + c0);
            const float4 fA0 = *(const float4*)(pA);
            const float4 fA1 = *(const float4*)(pA + 4);
            const float4 fA2 = *(const float4*)(pA + 8);
            const float  fAc = pA[12];
            const float4 fB0 = *(const float4*)(pB);
            const float4 fB1 = *(const float4*)(pB + 4);
            const float4 fB2 = *(const float4*)(pB + 8);
            const float  fBc = pB[12];
            const float afA[ED] = {fA0.x, fA0.y, fA0.z, fA0.w, fA1.x, fA1.y,
                                   fA1.z, fA1.w, fA2.x, fA2.y, fA2.z, fA2.w, fAc};
            const float afB[ED] = {fB0.x, fB0.y, fB0.z, fB0.w, fB1.x, fB1.y,
                                   fB1.z, fB1.w, fB2.x, fB2.y, fB2.z, fB2.w, fBc};
            float mA0 = bb0, mA1 = bb1, mB0 = bb0, mB1 = bb1;
#pragma unroll
            for (int k = 0; k < ED; ++k) {
                mA0 += afA[k] * w0[k];
                mA1 += afA[k] * w1[k];
                mB0 += afB[k] * w0[k];
                mB1 += afB[k] * w1[k];
            }
            a0 += fmaxf(mA0 + lo16(hA), 0.f) + fmaxf(mB0 + lo16(hB), 0.f);
            a1 += fmaxf(mA1 + hi16(hA), 0.f) + fmaxf(mB1 + hi16(hB), 0.f);
        }
        if (e < r1) {   // odd tail
            const unsigned int s = __builtin_amdgcn_readfirstlane(g_ssrc[e]);
            const float* sp = g_seat + (size_t)e * 16;
            const unsigned int hs = *(const unsigned int*)(hid + (size_t)s * H + c0);
            const float4 f0 = *(const float4*)(sp);
            const float4 f1 = *(const float4*)(sp + 4);
            const float4 f2 = *(const float4*)(sp + 8);
            const float  fc = sp[12];
            const float af[ED] = {f0.x, f0.y, f0.z, f0.w, f1.x, f1.y, f1.z,
                                  f1.w, f2.x, f2.y, f2.z, f2.w, fc};
            float m0 = bb0, m1 = bb1;
#pragma unroll
            for (int k = 0; k < ED; ++k) {
                m0 += af[k] * w0[k];
                m1 += af[k] * w1[k];
            }
            a0 += fmaxf(m0 + lo16(hs), 0.f);
            a1 += fmaxf(m1 + hi16(hs), 0.f);
        }
        *(unsigned int*)(hsum + (size_t)node * H + c0) = pk2(a0, a1);
    }
}

// ------------------------------------------------------------ MFMA GEMM
// (R7-proven structure: BM=64 BN=256 BK=64, single-buffer, (256,4))
// MODE 0: Cb = bf16(act(acc+bias)).
// MODE 2: pooled-t1 epilogue — v = relu(acc+bias); atomicAdd into
//         g_P[batch[row]*GH + batOff + col] with run-collapse on sorted batch.
template <int MODE>
__global__ __launch_bounds__(256, 4) void gemm_mfma(
        const unsigned short* __restrict__ A, int bsel,
        unsigned short* __restrict__ Cb,
        const void* __restrict__ batch, size_t batOff, int doRelu) {
    __shared__ unsigned short As[64 * 64];    // 8 KB, swizzled
    __shared__ unsigned short Bs[256 * 64];   // 32 KB, n-major [n][k], swizzled
    const int tid  = threadIdx.x;
    const int lane = tid & 63;
    const int wave = tid >> 6;
    const int m0   = blockIdx.x * 64;

    const unsigned short* Bt = bsel == 0 ? g_W1t
                             : bsel == 1 ? g_Wl1t[0] : g_Wl1t[1];
    const float* bias = bsel == 0 ? g_b1
                      : bsel == 1 ? g_bl1 : g_bl1 + 256;

    const int ar   = tid >> 2;
    const int ac   = (tid & 3) << 4;
    const int awb  = (ar << 7) + (ac << 1);
    const int aswz = (ar & 7) << 4;
    const size_t arow = (size_t)(m0 + ar) * H + ac;
    const int nrow = lane >> 3;
    const int kbu  = ((lane & 7) ^ nrow) << 4;

    f32x4 acc0[8], acc1[8];
    const f32x4 zz = {0.f, 0.f, 0.f, 0.f};
#pragma unroll
    for (int i = 0; i < 8; ++i) { acc0[i] = zz; acc1[i] = zz; }

    const int fr   = lane & 15;
    const int fg   = lane >> 4;
    const int rowb = (wave >> 1) << 5;   // 0 / 32
    const int colb = (wave & 1) << 7;    // 0 / 128

    for (int kt = 0; kt < 4; ++kt) {
#pragma unroll
        for (int j = 0; j < 8; ++j) {
            const int q = (wave << 3) + j;
            gload_lds16((const char*)Bt + (((size_t)(q << 3) + nrow) << 9)
                            + (kt << 7) + kbu,
                        (char*)Bs + (q << 10));
        }
        {
            const size_t aoff = arow + (kt << 6);
            uint4 w0 = *(const uint4*)(A + aoff);
            uint4 w1 = *(const uint4*)(A + aoff + 8);
            *(uint4*)((char*)As + (awb ^ aswz)) = w0;
            *(uint4*)((char*)As + ((awb + 16) ^ aswz)) = w1;
        }
        __syncthreads();   // drains vmcnt (global_load_lds) + lgkmcnt
#pragma unroll
        for (int s = 0; s < 2; ++s) {
            const int kofs = (s << 6) + (fg << 4);
            const int r0 = rowb + fr;
            short8 aF0 = *(const short8*)((const char*)As +
                          ((r0 << 7) + (kofs ^ ((r0 & 7) << 4))));
            short8 aF1 = *(const short8*)((const char*)As +
                          (((r0 + 16) << 7) + (kofs ^ ((r0 & 7) << 4))));
#pragma unroll
            for (int ct = 0; ct < 8; ++ct) {
                const int cc = colb + (ct << 4) + fr;
                short8 bF = *(const short8*)((const char*)Bs +
                             ((cc << 7) + (kofs ^ ((cc & 7) << 4))));
                acc0[ct] = __builtin_amdgcn_mfma_f32_16x16x32_bf16(aF0, bF, acc0[ct], 0, 0, 0);
                acc1[ct] = __builtin_amdgcn_mfma_f32_16x16x32_bf16(aF1, bF, acc1[ct], 0, 0, 0);
            }
        }
        __syncthreads();
    }

    const int crow = m0 + rowb + (fg << 2);
    if (MODE == 0) {
#pragma unroll
        for (int ct = 0; ct < 8; ++ct) {
            const int cc = colb + (ct << 4) + fr;
            const float bc = bias[cc];
#pragma unroll
            for (int r = 0; r < 4; ++r) {
                float v0 = acc0[ct][r] + bc;
                float v1 = acc1[ct][r] + bc;
                if (doRelu) { v0 = fmaxf(v0, 0.f); v1 = fmaxf(v1, 0.f); }
                Cb[(size_t)(crow + r) * H + cc]      = bfbits(v0);
                Cb[(size_t)(crow + 16 + r) * H + cc] = bfbits(v1);
            }
        }
    } else {
        // pooled t1: P[g] += relu(acc+bias), run-collapsed (batch sorted)
        const bool is64 = sniff_i64(batch, N_NODES / 2);
        int ga[5], gb[5];
#pragma unroll
        for (int r = 0; r < 4; ++r) {
            int g0 = ldi(batch, (size_t)(crow + r), is64);
            int g1 = ldi(batch, (size_t)(crow + 16 + r), is64);
            ga[r] = ((unsigned)g0 < (unsigned)NGRAPHS) ? g0 : 0;
            gb[r] = ((unsigned)g1 < (unsigned)NGRAPHS) ? g1 : 0;
        }
#pragma unroll
        for (int ct = 0; ct < 8; ++ct) {
            const int cc = colb + (ct << 4) + fr;
            const float bc = bias[cc];
            float run0 = 0.f, run1 = 0.f;
#pragma unroll
            for (int r = 0; r < 4; ++r) {
                run0 += fmaxf(acc0[ct][r] + bc, 0.f);
                if (r == 3 || ga[r + 1] != ga[r]) {
                    atomicAdd(&g_P[(size_t)ga[r] * GH + batOff + cc], run0);
                    run0 = 0.f;
                }
                run1 += fmaxf(acc1[ct][r] + bc, 0.f);
                if (r == 3 || gb[r + 1] != gb[r]) {
                    atomicAdd(&g_P[(size_t)gb[r] * GH + batOff + cc], run1);
                    run1 = 0.f;
                }
            }
        }
    }
}

// ----------------------------------------- final: out = P @ Wl2 + cnt*bl2
// Block owns 4 graphs; P rows staged in LDS; Wl2 raw input (k-major ->
// coalesced across lanes, L2-resident). 2.1 GF total.
__global__ __launch_bounds__(256) void final_out(
        const void* __restrict__ Wl2, float* __restrict__ out) {
    const bool isbf = sniff_bf16(Wl2);
    __shared__ float Pl[4 * GH];   // 8 KB
    const int g0 = blockIdx.x * 4;
    for (int i = threadIdx.x; i < 4 * GH; i += 256)
        Pl[i] = g_P[(size_t)g0 * GH + i];
    __syncthreads();
    const int c = threadIdx.x;
    const float b2 = g_bl2[c];
    float a0 = g_cntf[g0]     * b2;
    float a1 = g_cntf[g0 + 1] * b2;
    float a2 = g_cntf[g0 + 2] * b2;
    float a3 = g_cntf[g0 + 3] * b2;
#pragma unroll 8
    for (int k = 0; k < GH; ++k) {
        const float w = ldf(Wl2, (size_t)k * OUT_C + c, isbf);
        a0 += Pl[k] * w;
        a1 += Pl[GH + k] * w;
        a2 += Pl[2 * GH + k] * w;
        a3 += Pl[3 * GH + k] * w;
    }
    out[(size_t)g0 * OUT_C + c]           = a0;
    out[(size_t)(g0 + 1) * OUT_C + c]     = a1;
    out[(size_t)(g0 + 2) * OUT_C + c]     = a2;
    out[(size_t)(g0 + 3) * OUT_C + c]     = a3;
}

// ---------------------------------------------------------------- launcher
extern "C" void kernel_launch(void* const* d_in, const int* in_sizes, int n_in,
                              void* d_out, int out_size, void* d_ws, size_t ws_size,
                              hipStream_t stream) {
    const void *x = nullptr, *eattr = nullptr, *eidx = nullptr, *batch = nullptr;
    const void *W_nh = nullptr, *W1 = nullptr, *We = nullptr, *be = nullptr;
    const void *Wl1 = nullptr, *Wl2 = nullptr, *bl1 = nullptr;
    const void *z256[3] = {nullptr, nullptr, nullptr};
    int nz = 0;
    for (int i = 0; i < n_in; ++i) {
        switch (in_sizes[i]) {
            case N_NODES * NC:     x     = d_in[i]; break;
            case N_EDGES * ED:     eattr = d_in[i]; break;
            case 2 * N_EDGES:      eidx  = d_in[i]; break;
            case N_NODES:          batch = d_in[i]; break;
            case NC * H:           W_nh  = d_in[i]; break;
            case H * H:            W1    = d_in[i]; break;
            case NLAYERS * ED * H: We    = d_in[i]; break;
            case NLAYERS * H:      be    = d_in[i]; break;
            case H * GH:           if (!Wl1) Wl1 = d_in[i]; else Wl2 = d_in[i]; break;
            case GH:               bl1   = d_in[i]; break;
            case H:                if (nz < 3) z256[nz++] = d_in[i]; break;
            default: break;
        }
    }
    const void* b_nh = z256[0];
    const void* b1   = (nz > 1) ? z256[1] : z256[0];
    const void* bl2  = (nz > 2) ? z256[2] : z256[0];
    float* out = (float*)d_out;   // reference output dtype is FLOAT32

    if (!x || !eattr || !eidx || !batch || !W_nh || !W1 || !We || !be ||
        !Wl1 || !Wl2 || !bl1 || !b_nh) {
        fill_f4<<<1024, 256, 0, stream>>>((float4*)out, NGRAPHS * OUT_C / 4, 2.0e6f);
        return;  // sentinel: size-mapping failed
    }

    const size_t NH = (size_t)N_NODES * H;
    const size_t need = NH * 2 + NH * 2;   // hid + hsum, bf16 = 256 MiB
    if (ws_size < need) {
        fill_f4<<<1024, 256, 0, stream>>>((float4*)out, NGRAPHS * OUT_C / 4, 1.0e6f);
        return;  // sentinel: ws too small
    }
    bf16* hid            = (bf16*)d_ws;
    unsigned short* hsum = (unsigned short*)((char*)d_ws + NH * 2);

    // pack weights (transposed, bf16) + biases (fp32) into device globals
    pack_wt<<<256, 256, 0, stream>>>(W1,  H,     0,   0, 0);
    pack_wt<<<256, 256, 0, stream>>>(Wl1, GH,    0,   0, 1);
    pack_wt<<<256, 256, 0, stream>>>(Wl1, GH,    0, 256, 2);
    pack_bias<<<1, 256, 0, stream>>>(b1, bl1, bl2);

    // ---- build dst-sorted CSR once per launch (device-global storage)
    csr_zero<<<N_NODES / 256, 256, 0, stream>>>();
    hist_dst<<<N_EDGES / 256, 256, 0, stream>>>(eidx);
    scan1<<<N_NODES / 256, 256, 0, stream>>>();
    scan2<<<1, 256, 0, stream>>>();
    scan3<<<N_NODES / 256, 256, 0, stream>>>();
    scatter_e<<<N_EDGES / 256, 256, 0, stream>>>(eidx, eattr);

    node_proj<<<N_NODES / 16, 256, 0, stream>>>(x, W_nh, b_nh, hid);

    for (int l = 0; l < NLAYERS; ++l) {
        // hsum = hid + agg  (wave-pair per node, 2-edge unroll — proven)
        gine_agg<<<N_NODES / 16, 256, 0, stream>>>(
            We, (size_t)l * ED * H, be, (size_t)l * H,
            (const unsigned short*)hid, hsum);
        // hid = relu(hsum @ W1 + b1)
        gemm_mfma<0><<<N_NODES / 64, 256, 0, stream>>>(
            hsum, 0, (unsigned short*)hid, nullptr, 0, 1);
    }

    // ---- readout: pooling commutes with Wl2.
    // P[g] = sum_{n in g} relu(hid@Wl1+bl1)[n]  (pooled in GEMM epilogue);
    // out  = P @ Wl2 + cnt*bl2  (tiny final GEMM). No t0 round-trip.
    pzero<<<NGRAPHS * GH / 1024, 256, 0, stream>>>();
    czero<<<NGRAPHS / 256, 256, 0, stream>>>();
    hist_b<<<N_NODES / 256, 256, 0, stream>>>(batch);
    for (int c = 0; c < 2; ++c) {
        gemm_mfma<2><<<N_NODES / 64, 256, 0, stream>>>(
            (const unsigned short*)hid, 1 + c,
            nullptr, batch, (size_t)c * 256, 1);
    }
    final_out<<<NGRAPHS / 4, 256, 0, stream>>>(Wl2, out);
}

// Round 15
// 2131.254 us; speedup vs baseline: 1.2645x; 1.0667x over previous
//
#include <hip/hip_runtime.h>
#include <hip/hip_bf16.h>

#define N_NODES 262144
#define N_EDGES 1048576
#define NC      30
#define ED      13
#define H       256
#define GH      512
#define OUT_C   256
#define NLAYERS 4
#define NGRAPHS 8192

typedef __hip_bfloat16 bf16;
typedef __attribute__((ext_vector_type(8))) short short8;   // 8 bf16 = 4 VGPR
typedef __attribute__((ext_vector_type(4))) float f32x4;

// packed weights: bf16, N-major (Bt[n][k], k contiguous) + fp32 biases
__device__ unsigned short g_W1t[H * H];
__device__ unsigned short g_Wl1t[2][H * H];
__device__ float g_b1[H];
__device__ float g_bl1[GH];
__device__ float g_bl2[OUT_C];
// CSR (device-resident so d_ws only needs hid+hsum = 256 MiB)
__device__ unsigned int g_ssrc[N_EDGES];          // 4 MiB, src ids dst-sorted
__device__ float        g_seat[N_EDGES * 16];     // 64 MiB, eattr dst-sorted, padded
__device__ unsigned int g_rowptr[N_NODES + 1];    // 1 MiB
__device__ unsigned int g_cursor[N_NODES];        // 1 MiB (hist cnt, then cursor)
__device__ unsigned int g_bsum[1024];
// pooled-readout state: P[g] = sum of t1 rows of graph g; cntf[g] = #nodes
__device__ float g_P[NGRAPHS * GH];               // 16 MiB
__device__ float g_cntf[NGRAPHS];

__device__ __forceinline__ float hw2f(unsigned short h) {
    return __uint_as_float(((unsigned int)h) << 16);
}
__device__ __forceinline__ float ldf(const void* p, size_t i, bool isbf) {
    return isbf ? hw2f(((const unsigned short*)p)[i]) : ((const float*)p)[i];
}
__device__ __forceinline__ int ldi(const void* p, size_t j, bool is64) {
    return ((const int*)p)[is64 ? 2 * j : j];   // little-endian lo word
}
__device__ __forceinline__ unsigned short bfbits(float f) {
    bf16 b = __float2bfloat16(f);
    return *(unsigned short*)&b;
}
__device__ __forceinline__ float lo16(unsigned int u) { return __uint_as_float(u << 16); }
__device__ __forceinline__ float hi16(unsigned int u) { return __uint_as_float(u & 0xFFFF0000u); }
__device__ __forceinline__ unsigned int pk2(float a, float b) {
    return (unsigned int)bfbits(a) | ((unsigned int)bfbits(b) << 16);
}
// float width sniff: even halfwords. bf16 data -> plausible exponents.
__device__ __forceinline__ bool sniff_bf16(const void* xv) {
    const unsigned short* q = (const unsigned short*)xv;
    int c = 0;
    for (int i = 0; i < 32; ++i) {
        unsigned short h = q[2 * i];
        int e = (h >> 7) & 0xFF;
        c += (h == 0 || (e >= 97 && e <= 141)) ? 1 : 0;
    }
    return c >= 20;
}
// int width sniff: odd 32-bit words all zero <=> int64 (values < 2^31).
__device__ __forceinline__ bool sniff_i64(const void* pv, size_t baseWord) {
    const unsigned int* q = (const unsigned int*)pv;
    int z = 0;
    for (int i = 0; i < 32; ++i) z += (q[baseWord + 2 * i + 1] == 0) ? 1 : 0;
    return z >= 20;
}
// async global->LDS, 16B per lane; dst is wave-uniform base + lane*16
__device__ __forceinline__ void gload_lds16(const void* g, void* l) {
    __builtin_amdgcn_global_load_lds(
        (const __attribute__((address_space(1))) unsigned int*)g,
        (__attribute__((address_space(3))) unsigned int*)l, 16, 0, 0);
}

// ---------------------------------------------------------------- fills
__global__ __launch_bounds__(256) void fill_f4(float4* p, int n4, float val) {
    int i = blockIdx.x * 256 + threadIdx.x;
    int stride = gridDim.x * 256;
    float4 z = make_float4(val, val, val, val);
    for (; i < n4; i += stride) p[i] = z;
}
__global__ __launch_bounds__(256) void pzero() {       // grid 4096
    ((float4*)g_P)[blockIdx.x * 256 + threadIdx.x] = make_float4(0.f, 0.f, 0.f, 0.f);
}
__global__ __launch_bounds__(256) void czero() {       // grid 32
    g_cntf[blockIdx.x * 256 + threadIdx.x] = 0.f;
}
__global__ __launch_bounds__(256) void hist_b(const void* __restrict__ batch) {
    const bool is64 = sniff_i64(batch, N_NODES / 2);
    const int n = blockIdx.x * 256 + threadIdx.x;
    int g = ldi(batch, (size_t)n, is64);
    if ((unsigned)g >= (unsigned)NGRAPHS) g = 0;
    atomicAdd(&g_cntf[g], 1.0f);
}

// ---------------------------------------------------- weight / bias packers
// out[n][k] = in[k0+k][n0+n]  (transpose + bf16-normalize), 256x256 chunk
__global__ __launch_bounds__(256) void pack_wt(const void* __restrict__ in,
        int ldin, int k0, int n0, int which) {
    const bool isbf = sniff_bf16(in);
    unsigned short* outp = which == 0 ? g_W1t
                         : which == 1 ? g_Wl1t[0] : g_Wl1t[1];
    const int n = blockIdx.x, k = threadIdx.x;
    outp[(n << 8) + k] = bfbits(ldf(in, (size_t)(k0 + k) * ldin + n0 + n, isbf));
}
__global__ __launch_bounds__(256) void pack_bias(const void* b1, const void* bl1,
                                                 const void* bl2) {
    const int t = threadIdx.x;
    const bool s1 = sniff_bf16(b1), s2 = sniff_bf16(bl1), s3 = sniff_bf16(bl2);
    g_b1[t]        = ldf(b1,  t,       s1);
    g_bl1[t]       = ldf(bl1, t,       s2);
    g_bl1[t + 256] = ldf(bl1, t + 256, s2);
    g_bl2[t]       = ldf(bl2, t,       s3);
}

// ------------------------------------------------------------- CSR build
__global__ __launch_bounds__(256) void csr_zero() {
    g_cursor[blockIdx.x * 256 + threadIdx.x] = 0u;
}
__global__ __launch_bounds__(256) void hist_dst(const void* __restrict__ eidx) {
    const bool is64 = sniff_i64(eidx, 0);
    const int e = blockIdx.x * 256 + threadIdx.x;
    int dst = ldi(eidx, (size_t)N_EDGES + e, is64);
    if ((unsigned)dst >= (unsigned)N_NODES) dst = 0;
    atomicAdd(&g_cursor[dst], 1u);
}
__global__ __launch_bounds__(256) void scan1() {
    __shared__ unsigned int sh[256];
    const int tid = threadIdx.x;
    sh[tid] = g_cursor[blockIdx.x * 256 + tid];
    __syncthreads();
    for (int s = 128; s > 0; s >>= 1) {
        if (tid < s) sh[tid] += sh[tid + s];
        __syncthreads();
    }
    if (tid == 0) g_bsum[blockIdx.x] = sh[0];
}
__global__ __launch_bounds__(256) void scan2() {
    __shared__ unsigned int sh[1024];
    const int tid = threadIdx.x;
    for (int j = tid; j < 1024; j += 256) sh[j] = g_bsum[j];
    __syncthreads();
    if (tid == 0) {
        unsigned int run = 0;
        for (int j = 0; j < 1024; ++j) { unsigned int t = sh[j]; sh[j] = run; run += t; }
    }
    __syncthreads();
    for (int j = tid; j < 1024; j += 256) g_bsum[j] = sh[j];
}
__global__ __launch_bounds__(256) void scan3() {
    __shared__ unsigned int sh[256];
    const int tid = threadIdx.x;
    const int i = blockIdx.x * 256 + tid;
    const unsigned int v = g_cursor[i];
    sh[tid] = v;
    __syncthreads();
    for (int ofs = 1; ofs < 256; ofs <<= 1) {
        unsigned int t = (tid >= ofs) ? sh[tid - ofs] : 0u;
        __syncthreads();
        sh[tid] += t;
        __syncthreads();
    }
    const unsigned int excl = sh[tid] - v + g_bsum[blockIdx.x];
    g_rowptr[i] = excl;
    g_cursor[i] = excl;
    if (i == N_NODES - 1) g_rowptr[N_NODES] = excl + v;
}
// scatter src ids and edge_attr rows (fp32, padded to 16) into dst order
__global__ __launch_bounds__(256) void scatter_e(
        const void* __restrict__ eidx, const void* __restrict__ eattr) {
    const bool is64 = sniff_i64(eidx, 0);
    const bool isbf = sniff_bf16(eattr);
    const int e = blockIdx.x * 256 + threadIdx.x;
    int src = ldi(eidx, e, is64);
    int dst = ldi(eidx, (size_t)N_EDGES + e, is64);
    if ((unsigned)src >= (unsigned)N_NODES) src = 0;
    if ((unsigned)dst >= (unsigned)N_NODES) dst = 0;
    unsigned int pos = atomicAdd(&g_cursor[dst], 1u);
    if (pos >= (unsigned)N_EDGES) return;   // safety
    g_ssrc[pos] = (unsigned int)src;
    float a[16];
#pragma unroll
    for (int k = 0; k < ED; ++k) a[k] = ldf(eattr, (size_t)e * ED + k, isbf);
    a[13] = 0.f; a[14] = 0.f; a[15] = 0.f;
    float* so = g_seat + (size_t)pos * 16;
#pragma unroll
    for (int k = 0; k < 4; ++k)
        *(float4*)(so + 4 * k) = *(float4*)(a + 4 * k);
}

// ------------------------------------------------- hid = x @ W_nh + b_nh
__global__ __launch_bounds__(256) void node_proj(
        const void* __restrict__ x, const void* __restrict__ W,
        const void* __restrict__ b, bf16* __restrict__ hid) {
    const bool isbf = sniff_bf16(x);
    __shared__ float xs[16 * NC];
    const int m0 = blockIdx.x * 16;
    for (int i = threadIdx.x; i < 16 * NC; i += 256)
        xs[i] = ldf(x, (size_t)m0 * NC + i, isbf);
    __syncthreads();
    const int col = threadIdx.x;
    float w[NC];
#pragma unroll
    for (int k = 0; k < NC; ++k) w[k] = ldf(W, (size_t)k * H + col, isbf);
    const float bias = ldf(b, col, isbf);
#pragma unroll 4
    for (int r = 0; r < 16; ++r) {
        float acc = bias;
#pragma unroll
        for (int k = 0; k < NC; ++k) acc += xs[r * NC + k] * w[k];
        hid[(size_t)(m0 + r) * H + col] = __float2bfloat16(acc);
    }
}

// --------------------------------------------- CSR aggregation (no atomics)
// (exact R7/R10/R12 kernel — 265 µs proven; fp32 throughout)
__global__ __launch_bounds__(256, 4) void gine_agg(
        const void* __restrict__ We, size_t weOff,
        const void* __restrict__ be, size_t beOff,
        const unsigned short* __restrict__ hid,
        unsigned short* __restrict__ hsum) {
    const bool isbf = sniff_bf16(We);
    const int lane = threadIdx.x & 63;
    const int wave = threadIdx.x >> 6;
    const int wh   = wave & 1;       // which 128-col half
    const int wp   = wave >> 1;      // wave-pair id within block
    const int c0 = 128 * wh + 2 * lane;
    float w0[ED], w1[ED];
#pragma unroll
    for (int k = 0; k < ED; ++k) {
        const size_t o = weOff + (size_t)k * H;
        w0[k] = ldf(We, o + c0,     isbf);
        w1[k] = ldf(We, o + c0 + 1, isbf);
    }
    const float bb0 = ldf(be, beOff + c0,     isbf);
    const float bb1 = ldf(be, beOff + c0 + 1, isbf);

    const int nbase = blockIdx.x * 16 + wp * 8;
    for (int j = 0; j < 8; ++j) {
        const int node = nbase + j;
        const unsigned int r0 = __builtin_amdgcn_readfirstlane(g_rowptr[node]);
        const unsigned int r1 = __builtin_amdgcn_readfirstlane(g_rowptr[node + 1]);
        const unsigned int hu = *(const unsigned int*)(hid + (size_t)node * H + c0);
        float a0 = lo16(hu);
        float a1 = hi16(hu);
        unsigned int e = r0;
        for (; e + 2 <= r1; e += 2) {
            const unsigned int sA = __builtin_amdgcn_readfirstlane(g_ssrc[e]);
            const unsigned int sB = __builtin_amdgcn_readfirstlane(g_ssrc[e + 1]);
            const float* pA = g_seat + (size_t)e * 16;
            const float* pB = pA + 16;
            const unsigned int hA = *(const unsigned int*)(hid + (size_t)sA * H + c0);
            const unsigned int hB = *(const unsigned int*)(hid + (size_t)sB * H + c0);
            const float4 fA0 = *(const float4*)(pA);
            const float4 fA1 = *(const float4*)(pA + 4);
            const float4 fA2 = *(const float4*)(pA + 8);
            const float  fAc = pA[12];
            const float4 fB0 = *(const float4*)(pB);
            const float4 fB1 = *(const float4*)(pB + 4);
            const float4 fB2 = *(const float4*)(pB + 8);
            const float  fBc = pB[12];
            const float afA[ED] = {fA0.x, fA0.y, fA0.z, fA0.w, fA1.x, fA1.y,
                                   fA1.z, fA1.w, fA2.x, fA2.y, fA2.z, fA2.w, fAc};
            const float afB[ED] = {fB0.x, fB0.y, fB0.z, fB0.w, fB1.x, fB1.y,
                                   fB1.z, fB1.w, fB2.x, fB2.y, fB2.z, fB2.w, fBc};
            float mA0 = bb0, mA1 = bb1, mB0 = bb0, mB1 = bb1;
#pragma unroll
            for (int k = 0; k < ED; ++k) {
                mA0 += afA[k] * w0[k];
                mA1 += afA[k] * w1[k];
                mB0 += afB[k] * w0[k];
                mB1 += afB[k] * w1[k];
            }
            a0 += fmaxf(mA0 + lo16(hA), 0.f) + fmaxf(mB0 + lo16(hB), 0.f);
            a1 += fmaxf(mA1 + hi16(hA), 0.f) + fmaxf(mB1 + hi16(hB), 0.f);
        }
        if (e < r1) {   // odd tail
            const unsigned int s = __builtin_amdgcn_readfirstlane(g_ssrc[e]);
            const float* sp = g_seat + (size_t)e * 16;
            const unsigned int hs = *(const unsigned int*)(hid + (size_t)s * H + c0);
            const float4 f0 = *(const float4*)(sp);
            const float4 f1 = *(const float4*)(sp + 4);
            const float4 f2 = *(const float4*)(sp + 8);
            const float  fc = sp[12];
            const float af[ED] = {f0.x, f0.y, f0.z, f0.w, f1.x, f1.y, f1.z,
                                  f1.w, f2.x, f2.y, f2.z, f2.w, fc};
            float m0 = bb0, m1 = bb1;
#pragma unroll
            for (int k = 0; k < ED; ++k) {
                m0 += af[k] * w0[k];
                m1 += af[k] * w1[k];
            }
            a0 += fmaxf(m0 + lo16(hs), 0.f);
            a1 += fmaxf(m1 + hi16(hs), 0.f);
        }
        *(unsigned int*)(hsum + (size_t)node * H + c0) = pk2(a0, a1);
    }
}

// ------------------------------------------------------------ MFMA GEMM
// (R7-proven structure: BM=64 BN=256 BK=64, single-buffer, (256,4))
// MODE 0: Cb = bf16(act(acc+bias)).
// MODE 2: pooled-t1 epilogue with LDS PRE-REDUCTION — the block's 64 sorted
//         rows span a contiguous graph range; pool relu(acc+bias) into a
//         16x256 f32 LDS buffer (reusing dead Bs; 0 extra LDS), then flush
//         ~800 global atomics/block instead of 4096 (R12's MODE2 was atomic-
//         throughput-bound at ~250 µs vs MODE0's 127). Out-of-range rows
//         (rare) fall back to direct atomics.
template <int MODE>
__global__ __launch_bounds__(256, 4) void gemm_mfma(
        const unsigned short* __restrict__ A, int bsel,
        unsigned short* __restrict__ Cb,
        const void* __restrict__ batch, size_t batOff, int doRelu) {
    __shared__ unsigned short As[64 * 64];    // 8 KB, swizzled
    __shared__ unsigned short Bs[256 * 64];   // 32 KB, n-major [n][k], swizzled
    const int tid  = threadIdx.x;
    const int lane = tid & 63;
    const int wave = tid >> 6;
    const int m0   = blockIdx.x * 64;

    const unsigned short* Bt = bsel == 0 ? g_W1t
                             : bsel == 1 ? g_Wl1t[0] : g_Wl1t[1];
    const float* bias = bsel == 0 ? g_b1
                      : bsel == 1 ? g_bl1 : g_bl1 + 256;

    const int ar   = tid >> 2;
    const int ac   = (tid & 3) << 4;
    const int awb  = (ar << 7) + (ac << 1);
    const int aswz = (ar & 7) << 4;
    const size_t arow = (size_t)(m0 + ar) * H + ac;
    const int nrow = lane >> 3;
    const int kbu  = ((lane & 7) ^ nrow) << 4;

    f32x4 acc0[8], acc1[8];
    const f32x4 zz = {0.f, 0.f, 0.f, 0.f};
#pragma unroll
    for (int i = 0; i < 8; ++i) { acc0[i] = zz; acc1[i] = zz; }

    const int fr   = lane & 15;
    const int fg   = lane >> 4;
    const int rowb = (wave >> 1) << 5;   // 0 / 32
    const int colb = (wave & 1) << 7;    // 0 / 128

    for (int kt = 0; kt < 4; ++kt) {
#pragma unroll
        for (int j = 0; j < 8; ++j) {
            const int q = (wave << 3) + j;
            gload_lds16((const char*)Bt + (((size_t)(q << 3) + nrow) << 9)
                            + (kt << 7) + kbu,
                        (char*)Bs + (q << 10));
        }
        {
            const size_t aoff = arow + (kt << 6);
            uint4 w0 = *(const uint4*)(A + aoff);
            uint4 w1 = *(const uint4*)(A + aoff + 8);
            *(uint4*)((char*)As + (awb ^ aswz)) = w0;
            *(uint4*)((char*)As + ((awb + 16) ^ aswz)) = w1;
        }
        __syncthreads();   // drains vmcnt (global_load_lds) + lgkmcnt
#pragma unroll
        for (int s = 0; s < 2; ++s) {
            const int kofs = (s << 6) + (fg << 4);
            const int r0 = rowb + fr;
            short8 aF0 = *(const short8*)((const char*)As +
                          ((r0 << 7) + (kofs ^ ((r0 & 7) << 4))));
            short8 aF1 = *(const short8*)((const char*)As +
                          (((r0 + 16) << 7) + (kofs ^ ((r0 & 7) << 4))));
#pragma unroll
            for (int ct = 0; ct < 8; ++ct) {
                const int cc = colb + (ct << 4) + fr;
                short8 bF = *(const short8*)((const char*)Bs +
                             ((cc << 7) + (kofs ^ ((cc & 7) << 4))));
                acc0[ct] = __builtin_amdgcn_mfma_f32_16x16x32_bf16(aF0, bF, acc0[ct], 0, 0, 0);
                acc1[ct] = __builtin_amdgcn_mfma_f32_16x16x32_bf16(aF1, bF, acc1[ct], 0, 0, 0);
            }
        }
        __syncthreads();
    }

    const int crow = m0 + rowb + (fg << 2);
    if (MODE == 0) {
#pragma unroll
        for (int ct = 0; ct < 8; ++ct) {
            const int cc = colb + (ct << 4) + fr;
            const float bc = bias[cc];
#pragma unroll
            for (int r = 0; r < 4; ++r) {
                float v0 = acc0[ct][r] + bc;
                float v1 = acc1[ct][r] + bc;
                if (doRelu) { v0 = fmaxf(v0, 0.f); v1 = fmaxf(v1, 0.f); }
                Cb[(size_t)(crow + r) * H + cc]      = bfbits(v0);
                Cb[(size_t)(crow + 16 + r) * H + cc] = bfbits(v1);
            }
        }
    } else {
        // pooled t1: LDS pre-reduce by local graph index, then flush
        float* pool = (float*)Bs;                    // 16 KB inside dead Bs
        for (int i = tid; i < 16 * 256; i += 256) pool[i] = 0.f;
        const bool is64 = sniff_i64(batch, N_NODES / 2);
        int gbase = ldi(batch, (size_t)m0, is64);
        if ((unsigned)gbase >= (unsigned)NGRAPHS) gbase = 0;
        int ga[5], gb[5];
#pragma unroll
        for (int r = 0; r < 4; ++r) {
            int g0 = ldi(batch, (size_t)(crow + r), is64);
            int g1 = ldi(batch, (size_t)(crow + 16 + r), is64);
            ga[r] = ((unsigned)g0 < (unsigned)NGRAPHS) ? g0 : 0;
            gb[r] = ((unsigned)g1 < (unsigned)NGRAPHS) ? g1 : 0;
        }
        __syncthreads();                             // pool zeros visible
#pragma unroll
        for (int ct = 0; ct < 8; ++ct) {
            const int cc = colb + (ct << 4) + fr;
            const float bc = bias[cc];
            float run0 = 0.f, run1 = 0.f;
#pragma unroll
            for (int r = 0; r < 4; ++r) {
                run0 += fmaxf(acc0[ct][r] + bc, 0.f);
                if (r == 3 || ga[r + 1] != ga[r]) {
                    const int gl = ga[r] - gbase;
                    if ((unsigned)gl < 16u) atomicAdd(&pool[gl * 256 + cc], run0);
                    else atomicAdd(&g_P[(size_t)ga[r] * GH + batOff + cc], run0);
                    run0 = 0.f;
                }
                run1 += fmaxf(acc1[ct][r] + bc, 0.f);
                if (r == 3 || gb[r + 1] != gb[r]) {
                    const int gl = gb[r] - gbase;
                    if ((unsigned)gl < 16u) atomicAdd(&pool[gl * 256 + cc], run1);
                    else atomicAdd(&g_P[(size_t)gb[r] * GH + batOff + cc], run1);
                    run1 = 0.f;
                }
            }
        }
        __syncthreads();
        for (int i = tid; i < 16 * 256; i += 256) {
            const float v = pool[i];
            const int gg = gbase + (i >> 8);
            if (v != 0.f && gg < NGRAPHS)
                atomicAdd(&g_P[(size_t)gg * GH + batOff + (i & 255)], v);
        }
    }
}

// ----------------------------------------- final: out = P @ Wl2 + cnt*bl2
// Block owns 4 graphs; P rows staged in LDS; Wl2 raw input (k-major ->
// coalesced across lanes, L2-resident). 2.1 GF total.
__global__ __launch_bounds__(256) void final_out(
        const void* __restrict__ Wl2, float* __restrict__ out) {
    const bool isbf = sniff_bf16(Wl2);
    __shared__ float Pl[4 * GH];   // 8 KB
    const int g0 = blockIdx.x * 4;
    for (int i = threadIdx.x; i < 4 * GH; i += 256)
        Pl[i] = g_P[(size_t)g0 * GH + i];
    __syncthreads();
    const int c = threadIdx.x;
    const float b2 = g_bl2[c];
    float a0 = g_cntf[g0]     * b2;
    float a1 = g_cntf[g0 + 1] * b2;
    float a2 = g_cntf[g0 + 2] * b2;
    float a3 = g_cntf[g0 + 3] * b2;
#pragma unroll 8
    for (int k = 0; k < GH; ++k) {
        const float w = ldf(Wl2, (size_t)k * OUT_C + c, isbf);
        a0 += Pl[k] * w;
        a1 += Pl[GH + k] * w;
        a2 += Pl[2 * GH + k] * w;
        a3 += Pl[3 * GH + k] * w;
    }
    out[(size_t)g0 * OUT_C + c]           = a0;
    out[(size_t)(g0 + 1) * OUT_C + c]     = a1;
    out[(size_t)(g0 + 2) * OUT_C + c]     = a2;
    out[(size_t)(g0 + 3) * OUT_C + c]     = a3;
}

// ---------------------------------------------------------------- launcher
extern "C" void kernel_launch(void* const* d_in, const int* in_sizes, int n_in,
                              void* d_out, int out_size, void* d_ws, size_t ws_size,
                              hipStream_t stream) {
    const void *x = nullptr, *eattr = nullptr, *eidx = nullptr, *batch = nullptr;
    const void *W_nh = nullptr, *W1 = nullptr, *We = nullptr, *be = nullptr;
    const void *Wl1 = nullptr, *Wl2 = nullptr, *bl1 = nullptr;
    const void *z256[3] = {nullptr, nullptr, nullptr};
    int nz = 0;
    for (int i = 0; i < n_in; ++i) {
        switch (in_sizes[i]) {
            case N_NODES * NC:     x     = d_in[i]; break;
            case N_EDGES * ED:     eattr = d_in[i]; break;
            case 2 * N_EDGES:      eidx  = d_in[i]; break;
            case N_NODES:          batch = d_in[i]; break;
            case NC * H:           W_nh  = d_in[i]; break;
            case H * H:            W1    = d_in[i]; break;
            case NLAYERS * ED * H: We    = d_in[i]; break;
            case NLAYERS * H:      be    = d_in[i]; break;
            case H * GH:           if (!Wl1) Wl1 = d_in[i]; else Wl2 = d_in[i]; break;
            case GH:               bl1   = d_in[i]; break;
            case H:                if (nz < 3) z256[nz++] = d_in[i]; break;
            default: break;
        }
    }
    const void* b_nh = z256[0];
    const void* b1   = (nz > 1) ? z256[1] : z256[0];
    const void* bl2  = (nz > 2) ? z256[2] : z256[0];
    float* out = (float*)d_out;   // reference output dtype is FLOAT32

    if (!x || !eattr || !eidx || !batch || !W_nh || !W1 || !We || !be ||
        !Wl1 || !Wl2 || !bl1 || !b_nh) {
        fill_f4<<<1024, 256, 0, stream>>>((float4*)out, NGRAPHS * OUT_C / 4, 2.0e6f);
        return;  // sentinel: size-mapping failed
    }

    const size_t NH = (size_t)N_NODES * H;
    const size_t need = NH * 2 + NH * 2;   // hid + hsum, bf16 = 256 MiB
    if (ws_size < need) {
        fill_f4<<<1024, 256, 0, stream>>>((float4*)out, NGRAPHS * OUT_C / 4, 1.0e6f);
        return;  // sentinel: ws too small
    }
    bf16* hid            = (bf16*)d_ws;
    unsigned short* hsum = (unsigned short*)((char*)d_ws + NH * 2);

    // pack weights (transposed, bf16) + biases (fp32) into device globals
    pack_wt<<<256, 256, 0, stream>>>(W1,  H,  0,   0, 0);
    pack_wt<<<256, 256, 0, stream>>>(Wl1, GH, 0,   0, 1);
    pack_wt<<<256, 256, 0, stream>>>(Wl1, GH, 0, 256, 2);
    pack_bias<<<1, 256, 0, stream>>>(b1, bl1, bl2);

    // ---- build dst-sorted CSR once per launch (device-global storage)
    csr_zero<<<N_NODES / 256, 256, 0, stream>>>();
    hist_dst<<<N_EDGES / 256, 256, 0, stream>>>(eidx);
    scan1<<<N_NODES / 256, 256, 0, stream>>>();
    scan2<<<1, 256, 0, stream>>>();
    scan3<<<N_NODES / 256, 256, 0, stream>>>();
    scatter_e<<<N_EDGES / 256, 256, 0, stream>>>(eidx, eattr);

    node_proj<<<N_NODES / 16, 256, 0, stream>>>(x, W_nh, b_nh, hid);

    for (int l = 0; l < NLAYERS; ++l) {
        // hsum = hid + agg  (wave-pair per node, 2-edge unroll — proven)
        gine_agg<<<N_NODES / 16, 256, 0, stream>>>(
            We, (size_t)l * ED * H, be, (size_t)l * H,
            (const unsigned short*)hid, hsum);
        // hid = relu(hsum @ W1 + b1)
        gemm_mfma<0><<<N_NODES / 64, 256, 0, stream>>>(
            hsum, 0, (unsigned short*)hid, nullptr, 0, 1);
    }

    // ---- readout: pooling commutes with Wl2.
    // P[g] = sum_{n in g} relu(hid@Wl1+bl1)[n]  (pooled in GEMM epilogue,
    // LDS pre-reduced); out = P @ Wl2 + cnt*bl2.
    pzero<<<NGRAPHS * GH / 1024, 256, 0, stream>>>();
    czero<<<NGRAPHS / 256, 256, 0, stream>>>();
    hist_b<<<N_NODES / 256, 256, 0, stream>>>(batch);
    for (int c = 0; c < 2; ++c) {
        gemm_mfma<2><<<N_NODES / 64, 256, 0, stream>>>(
            (const unsigned short*)hid, 1 + c,
            nullptr, batch, (size_t)c * 256, 1);
    }
    final_out<<<NGRAPHS / 4, 256, 0, stream>>>(Wl2, out);
}